// Round 4
// baseline (31582.764 us; speedup 1.0000x reference)
//
#include <hip/hip_runtime.h>
#include <hip/hip_bf16.h>
#include <stdint.h>

// Dims
#define STEPS  200
#define KA     1792   // p(256) + ctx(512) + ah(1024)
#define KD     2560   // ah(1024) + ctx(512) + dh(1024)
#define NBLK   256
#define JLA    56     // KA/32 frag-iters (all LDS)
#define JLD    72     // D frag-iters in LDS (K 0..2304)
#define JTD    80     // KD/32 total
#define WLDS_A (JLA*2*64*16)   // 114688 B
#define WLDS_D (JLD*2*64*16)   // 147456 B
#define DSMEM  147456

using bf16 = __bf16;
typedef __bf16 bf16x8 __attribute__((ext_vector_type(8)));
typedef float  f32x4  __attribute__((ext_vector_type(4)));
typedef unsigned int       u32;
typedef unsigned long long u64;

union U8v { u64 q[2]; bf16x8 v; };
union U2f { u64 q; float f[2]; };
union U2h { u32 u; bf16 h[2]; };
union U4h { u32 u[2]; bf16 h[4]; };

#define MFMA16(a,b,c) __builtin_amdgcn_mfma_f32_16x16x32_bf16((a),(b),(c),0,0,0)

__device__ __forceinline__ float sigf(float x){ return 1.f/(1.f+__expf(-x)); }
__device__ __forceinline__ float tanhf_(float x){
  float ax = fabsf(x);
  float e  = __expf(-2.f*ax);
  float t  = (1.f-e)/(1.f+e);
  return x < 0.f ? -t : t;
}

// coherent (agent-scope, LLC) accessors — no cache maintenance
__device__ __forceinline__ u64 ldq(const u64* p){
  return __hip_atomic_load((u64*)p, __ATOMIC_RELAXED, __HIP_MEMORY_SCOPE_AGENT);
}
__device__ __forceinline__ void stf(float* p, float v){
  __hip_atomic_store(p, v, __ATOMIC_RELAXED, __HIP_MEMORY_SCOPE_AGENT);
}
__device__ __forceinline__ void stu(u32* p, u32 v){
  __hip_atomic_store(p, v, __ATOMIC_RELAXED, __HIP_MEMORY_SCOPE_AGENT);
}

// ---------------- prologue conversion kernels ----------------
__global__ void cvt_kernel(const float* __restrict__ s, bf16* __restrict__ d, int n){
  int i = blockIdx.x*256 + threadIdx.x;
  if (i < n) d[i] = (bf16)s[i];
}
__global__ void cvt_pad_kernel(const float* __restrict__ s, bf16* __restrict__ d,
                               int rows, int cin, int cout){
  int i = blockIdx.x*256 + threadIdx.x;
  if (i >= rows*cout) return;
  int r = i / cout, c = i % cout;
  d[i] = (bf16)(c < cin ? s[(size_t)r*cin + c] : 0.f);
}
__global__ void cat_cvt_kernel(const float* __restrict__ s1, int c1,
                               const float* __restrict__ s2, int c2,
                               bf16* __restrict__ d, int rows){
  int C = c1 + c2;
  int i = blockIdx.x*256 + threadIdx.x;
  if (i >= rows*C) return;
  int r = i / C, c = i % C;
  float v = (c < c1) ? s1[(size_t)r*c1 + c] : s2[(size_t)r*c2 + (c - c1)];
  d[i] = (bf16)v;
}
__global__ void build_wmelcat(const float* __restrict__ Wmel, const float* __restrict__ Wstop,
                              bf16* __restrict__ d){
  int i = blockIdx.x*256 + threadIdx.x;
  if (i >= 176*1536) return;
  int r = i / 1536, c = i % 1536;
  float v = (r < 160) ? Wmel[(size_t)r*1536 + c] : (r == 160 ? Wstop[c] : 0.f);
  d[i] = (bf16)v;
}
__global__ void build_misc(const float* biha, const float* bhha, float* biasa,
                           const float* bihd, const float* bhhd, float* biasd,
                           const float* bmel, const float* bstop, float* bias176){
  int i = blockIdx.x*256 + threadIdx.x;
  if (i < 4096) biasa[i] = biha[i] + bhha[i];
  else if (i < 8192) { int j = i-4096; biasd[j] = bihd[j] + bhhd[j]; }
  else if (i < 8192+176) {
    int j = i - 8192;
    bias176[j] = (j < 160) ? bmel[j] : (j == 160 ? bstop[0] : 0.f);
  }
}
__global__ void build_decin(const float* __restrict__ inp, bf16* __restrict__ d){
  int i = blockIdx.x*256 + threadIdx.x;
  if (i >= 12800*96) return;
  int row = i / 96, c = i % 96;
  int s = row >> 6, b = row & 63;
  float v = 0.f;
  if (c < 80 && s > 0) v = inp[((size_t)b*400 + (2*s - 1))*80 + c];
  d[i] = (bf16)v;
}

// ---------------- generic MFMA GEMM (prologue/epilogue batched use) ----------------
template<int ACT, int OBF>
__global__ __launch_bounds__(256)
void gemm_k(const bf16* __restrict__ A, const bf16* __restrict__ Bm,
            const float* __restrict__ bias, float* __restrict__ Cf,
            bf16* __restrict__ Cb, int M, int N, int K, int MT)
{
  int wid = blockIdx.x*4 + (threadIdx.x >> 6);
  if (wid >= MT*(N >> 4)) return;
  int wm = wid % MT, wn = wid / MT;
  int l = threadIdx.x & 63, lo = l & 15, hi = l >> 4;
  const bf16* Bp = Bm + (size_t)(wn*16 + lo)*K + hi*8;
  const bf16* Ap = A  + (size_t)(wm*64 + lo)*K + hi*8;
  f32x4 acc0 = {0,0,0,0}, acc1 = {0,0,0,0}, acc2 = {0,0,0,0}, acc3 = {0,0,0,0};
  for (int k = 0; k < K; k += 32){
    bf16x8 bb = *(const bf16x8*)(Bp + k);
    bf16x8 a0 = *(const bf16x8*)(Ap + k);
    bf16x8 a1 = *(const bf16x8*)(Ap + (size_t)16*K + k);
    bf16x8 a2 = *(const bf16x8*)(Ap + (size_t)32*K + k);
    bf16x8 a3 = *(const bf16x8*)(Ap + (size_t)48*K + k);
    acc0 = MFMA16(a0, bb, acc0);
    acc1 = MFMA16(a1, bb, acc1);
    acc2 = MFMA16(a2, bb, acc2);
    acc3 = MFMA16(a3, bb, acc3);
  }
  int n = wn*16 + lo;
  float bv = bias ? bias[n] : 0.f;
  int m0 = wm*64 + hi*4;
  #pragma unroll
  for (int mt = 0; mt < 4; ++mt){
    f32x4 av = (mt==0)?acc0:(mt==1)?acc1:(mt==2)?acc2:acc3;
    #pragma unroll
    for (int r = 0; r < 4; ++r){
      float v = av[r] + bv;
      if (ACT) v = fmaxf(v, 0.f);
      size_t idx = (size_t)(m0 + mt*16 + r)*N + n;
      if (OBF) Cb[idx] = (bf16)v; else Cf[idx] = v;
    }
  }
}

// ---------------- grid barrier: NO cache maintenance ------------------------------
__device__ __forceinline__ void gridbar(unsigned* cnt, unsigned target){
  __syncthreads();
  if (threadIdx.x == 0){
    asm volatile("s_waitcnt vmcnt(0)" ::: "memory");
    __hip_atomic_fetch_add(cnt, 1u, __ATOMIC_RELAXED, __HIP_MEMORY_SCOPE_AGENT);
    while (__hip_atomic_load(cnt, __ATOMIC_RELAXED, __HIP_MEMORY_SCOPE_AGENT) < target)
      __builtin_amdgcn_s_sleep(2);
    asm volatile("" ::: "memory");
  }
  __syncthreads();
}

// ---------------- THE persistent scan kernel ---------------------------------------
// 256 blocks x 256 thr, 1/CU. Weights LDS-resident (fragment-major):
//   blocks 0-127: A-GEMM tile rows [bq*32,+32) of 4096, K=1792 all in LDS (112 KiB)
//   blocks 128-255: D-GEMM tile, K 0..2304 in LDS (144 KiB), K 2304..2560 from L2
// 4 waves split M (16 rows each), full-K accumulate -> no partials.
// Comm (xa, xd, ga, gd, cnt) via agent-scope relaxed atomics (LLC).
// Blocks 0-63 additionally run phase B (cells + attention) with LDS at +114688.
__global__ __launch_bounds__(256, 1)
void decoder_scan(const bf16* __restrict__ pall,
                  const bf16* __restrict__ Wa, const bf16* __restrict__ Wd,
                  const float* __restrict__ biasa, const float* __restrict__ biasd,
                  const bf16* __restrict__ Wqb, const float* __restrict__ Wconv,
                  const float* __restrict__ Wloc, const float* __restrict__ vvp,
                  const float* __restrict__ pm, const bf16* __restrict__ enc_bf,
                  bf16* __restrict__ xa, bf16* __restrict__ xd,
                  float* __restrict__ ga, float* __restrict__ gd,
                  float* __restrict__ ac, float* __restrict__ dc,
                  bf16* __restrict__ proj, float* __restrict__ out_attn,
                  unsigned* __restrict__ cnt)
{
  extern __shared__ char smem[];
  const int tid = threadIdx.x;
  const int l = tid & 63, lo = l & 15, hi = l >> 4;
  const int wv = tid >> 6;

  // phase-A assignment
  const bool isA  = blockIdx.x < 128;
  const int  bq   = isA ? blockIdx.x : blockIdx.x - 128;
  const int  n0   = bq * 32;
  const int  K    = isA ? KA : KD;
  const int  JL   = isA ? JLA : JLD;
  const bf16* Wg  = isA ? Wa : Wd;
  const bf16* X   = isA ? xa : xd;
  float*      G   = isA ? ga : gd;
  bf16* wlds = (bf16*)smem;

  // phase-B LDS overlay (blocks 0-63 only; region beyond A-weights)
  char* pb = smem + WLDS_A;
  bf16*  ahs  = (bf16*)pb;              // 2048 B
  float* locb = (float*)(pb + 2048);    // 200*32*4 = 25600
  float* awl  = (float*)(pb + 27648);   // 1024
  float* qp   = (float*)(pb + 28672);   // 1024
  float* qv   = (float*)(pb + 29696);   // 512
  float* es   = (float*)(pb + 30208);   // 1024
  float* sred = (float*)(pb + 31232);   // 64

  // ---- preload weights into LDS (fragment-major: frag (j,t) at (j*2+t)*64+lane) ----
  for (int j = wv; j < JL; j += 4){
    #pragma unroll
    for (int t = 0; t < 2; ++t){
      bf16x8 v = *(const bf16x8*)(Wg + (size_t)(n0 + t*16 + lo)*K + j*32 + hi*8);
      *(bf16x8*)(wlds + ((size_t)(j*2 + t)*64 + l)*8) = v;
    }
  }

  unsigned nb = 0;

  // pre-loop init (phase-B blocks)
  if (blockIdx.x < 64){
    const int b = blockIdx.x;
    if (tid < 256) awl[tid] = 0.f;
    if (tid < 128){
      u32 v = ((const u32*)(pall + (size_t)b*256))[tid];
      stu((u32*)(xa + (size_t)b*1792) + tid, v);
    }
  }
  __syncthreads();
  gridbar(cnt, ++nb * NBLK);

  for (int i = 0; i <= STEPS; ++i){
    // =========================== phase A: gate GEMM ===========================
    const bool work = isA ? (i < STEPS) : (i > 0);
    if (work){
      const int m0 = wv*16;
      const bf16* Xp = X + (size_t)(m0 + lo)*K + hi*8;
      const bf16* wl = wlds + (size_t)l*8;
      f32x4 acc0 = {0,0,0,0}, acc1 = {0,0,0,0};
      #pragma unroll 4
      for (int j = 0; j < JL; ++j){
        U8v a;
        const u64* ap = (const u64*)(Xp + j*32);
        a.q[0] = ldq(ap); a.q[1] = ldq(ap + 1);
        bf16x8 b0 = *(const bf16x8*)(wl + (size_t)(j*2    )*512);
        bf16x8 b1 = *(const bf16x8*)(wl + (size_t)(j*2 + 1)*512);
        acc0 = MFMA16(a.v, b0, acc0);
        acc1 = MFMA16(a.v, b1, acc1);
      }
      if (!isA){
        // streamed weight tail K in [2304, 2560) — small, L2-resident
        #pragma unroll
        for (int j = JLD; j < JTD; ++j){
          U8v a;
          const u64* ap = (const u64*)(Xp + j*32);
          a.q[0] = ldq(ap); a.q[1] = ldq(ap + 1);
          bf16x8 b0 = *(const bf16x8*)(Wg + (size_t)(n0 +      lo)*K + j*32 + hi*8);
          bf16x8 b1 = *(const bf16x8*)(Wg + (size_t)(n0 + 16 + lo)*K + j*32 + hi*8);
          acc0 = MFMA16(a.v, b0, acc0);
          acc1 = MFMA16(a.v, b1, acc1);
        }
      }
      // gates: batch row m = m0 + hi*4 + r; col n = n0 + t*16 + lo
      #pragma unroll
      for (int r = 0; r < 4; ++r){
        stf(&G[(size_t)(m0 + hi*4 + r)*4096 + n0 +      lo], acc0[r]);
        stf(&G[(size_t)(m0 + hi*4 + r)*4096 + n0 + 16 + lo], acc1[r]);
      }
    }
    gridbar(cnt, ++nb * NBLK);

    // =========================== phase B: state + attention ====================
    if (blockIdx.x < 64){
      const int b = blockIdx.x;
      const int u0 = tid*4;
      if (i > 0){
        // dec LSTM cell update (step i-1)
        const u64* gp = (const u64*)(gd + (size_t)b*4096);
        float gg[16];
        #pragma unroll
        for (int g = 0; g < 4; ++g){
          U2f x0, x1;
          x0.q = ldq(gp + ((g*1024 + u0) >> 1));
          x1.q = ldq(gp + ((g*1024 + u0) >> 1) + 1);
          gg[g*4+0]=x0.f[0]; gg[g*4+1]=x0.f[1]; gg[g*4+2]=x1.f[0]; gg[g*4+3]=x1.f[1];
        }
        U4h hp;
        #pragma unroll
        for (int j = 0; j < 4; ++j){
          int u = u0 + j;
          float iv=gg[j]+biasd[u], fv=gg[4+j]+biasd[1024+u];
          float gv=gg[8+j]+biasd[2048+u], ov=gg[12+j]+biasd[3072+u];
          float c = sigf(fv)*dc[b*1024+u] + sigf(iv)*tanhf_(gv);
          float h = sigf(ov)*tanhf_(c);
          dc[b*1024+u] = c;
          bf16 hb = (bf16)h;
          hp.h[j] = hb;
          proj[((size_t)(i-1)*64 + b)*1536 + u] = hb;
        }
        u32* xp = (u32*)(xd + (size_t)b*2560 + 1536 + u0);
        stu(xp, hp.u[0]); stu(xp+1, hp.u[1]);
      }
      if (i < STEPS){
        // attn LSTM cell update (step i)
        {
          const u64* gp = (const u64*)(ga + (size_t)b*4096);
          float gg[16];
          #pragma unroll
          for (int g = 0; g < 4; ++g){
            U2f x0, x1;
            x0.q = ldq(gp + ((g*1024 + u0) >> 1));
            x1.q = ldq(gp + ((g*1024 + u0) >> 1) + 1);
            gg[g*4+0]=x0.f[0]; gg[g*4+1]=x0.f[1]; gg[g*4+2]=x1.f[0]; gg[g*4+3]=x1.f[1];
          }
          U4h hp;
          #pragma unroll
          for (int j = 0; j < 4; ++j){
            int u = u0 + j;
            float iv=gg[j]+biasa[u], fv=gg[4+j]+biasa[1024+u];
            float gv=gg[8+j]+biasa[2048+u], ov=gg[12+j]+biasa[3072+u];
            float c = sigf(fv)*ac[b*1024+u] + sigf(iv)*tanhf_(gv);
            float h = sigf(ov)*tanhf_(c);
            ac[b*1024+u] = c;
            bf16 hb = (bf16)h;
            hp.h[j] = hb;
            ahs[u] = hb;
          }
          u32* xpa = (u32*)(xa + (size_t)b*1792 + 768 + u0);
          stu(xpa, hp.u[0]); stu(xpa+1, hp.u[1]);
          u32* xpd = (u32*)(xd + (size_t)b*2560 + u0);
          stu(xpd, hp.u[0]); stu(xpd+1, hp.u[1]);
        }
        // teacher-forced prenet input for step i+1
        if (i < STEPS-1 && tid < 128){
          u32 v = ((const u32*)(pall + ((size_t)(i+1)*64 + b)*256))[tid];
          stu((u32*)(xa + (size_t)b*1792) + tid, v);
        }
        __syncthreads();  // ahs ready
        // conv1d(31) of previous alignment
        for (int it = tid; it < 6400; it += 256){
          int f = it & 31, tl = it >> 5;
          float s = 0.f;
          #pragma unroll
          for (int j = 0; j < 31; ++j){
            int tt = tl + j - 15;
            if ((unsigned)tt < 200u) s += awl[tt]*Wconv[f*31+j];
          }
          locb[tl*32 + f] = s;
        }
        // q = ah @ Wq^T
        {
          int a = tid & 127, hf = tid >> 7;
          const bf16* wr = Wqb + (size_t)a*1024 + hf*512;
          float s = 0.f;
          for (int k2 = 0; k2 < 512; k2 += 8){
            bf16x8 x = *(const bf16x8*)(&ahs[hf*512 + k2]);
            bf16x8 y = *(const bf16x8*)(wr + k2);
            #pragma unroll
            for (int e = 0; e < 8; ++e) s += (float)x[e]*(float)y[e];
          }
          qp[tid] = s;
        }
        __syncthreads();
        if (tid < 128) qv[tid] = qp[tid] + qp[tid+128];
        __syncthreads();
        // energies
        {
          for (int tl = wv; tl < 200; tl += 4){
            const float* pmrow = pm + ((size_t)b*200 + tl)*128;
            float s = 0.f;
            #pragma unroll
            for (int half = 0; half < 2; ++half){
              int a = l + half*64;
              float x = qv[a] + pmrow[a];
              const float* wl2 = Wloc + a*32;
              #pragma unroll
              for (int f = 0; f < 32; ++f) x += locb[tl*32 + f]*wl2[f];
              s += vvp[a]*tanhf_(x);
            }
            #pragma unroll
            for (int o = 32; o; o >>= 1) s += __shfl_xor(s, o);
            if (l == 0) es[tl] = s;
          }
        }
        __syncthreads();
        // softmax over 200
        {
          float e0 = (tid < 200) ? es[tid] : -3.0e38f;
          float m = e0;
          #pragma unroll
          for (int o = 32; o; o >>= 1) m = fmaxf(m, __shfl_xor(m, o));
          if (l == 0) sred[wv] = m;
          __syncthreads();
          m = fmaxf(fmaxf(sred[0],sred[1]), fmaxf(sred[2],sred[3]));
          float p = (tid < 200) ? __expf(e0 - m) : 0.f;
          float ss = p;
          #pragma unroll
          for (int o = 32; o; o >>= 1) ss += __shfl_xor(ss, o);
          __syncthreads();
          if (l == 0) sred[wv] = ss;
          __syncthreads();
          ss = sred[0]+sred[1]+sred[2]+sred[3];
          float aval = p / ss;
          if (tid < 200){
            awl[tid] = aval;
            out_attn[((size_t)b*200 + i)*200 + tid] = aval;
          }
        }
        __syncthreads();
        // context = align @ enc  (2 adjacent dims per thread)
        {
          const u32* ep = (const u32*)(enc_bf + (size_t)b*102400) + tid;
          float s0 = 0.f, s1 = 0.f;
          #pragma unroll 4
          for (int t = 0; t < 200; ++t){
            U2h w; w.u = ep[(size_t)t*256];
            float a = awl[t];
            s0 += a*(float)w.h[0];
            s1 += a*(float)w.h[1];
          }
          U2h cb; cb.h[0] = (bf16)s0; cb.h[1] = (bf16)s1;
          stu((u32*)(xa + (size_t)b*1792 + 256)  + tid, cb.u);
          stu((u32*)(xd + (size_t)b*2560 + 1024) + tid, cb.u);
          *((u32*)(proj + ((size_t)i*64 + b)*1536 + 1024) + tid) = cb.u;
        }
      }
    }
    gridbar(cnt, ++nb * NBLK);
  }
}

// ---------------- epilogue scatter -------------------------------------------------
__global__ void scatter_out(const float* __restrict__ mt_, float* __restrict__ out){
  int i = blockIdx.x*256 + threadIdx.x;
  const int NMEL = 12800*160;
  if (i < NMEL){
    int sb = i / 160, j = i % 160;
    int s = sb >> 6, b = sb & 63;
    int r = j / 80, mm = j % 80;
    out[((size_t)b*400 + 2*s + r)*80 + mm] = mt_[(size_t)sb*176 + j];
  } else if (i < NMEL + 12800){
    int sb = i - NMEL;
    int s = sb >> 6, b = sb & 63;
    float st = sigf(mt_[(size_t)sb*176 + 160]);
    float* so = out + 2048000;
    so[(size_t)b*400 + 2*s]     = st;
    so[(size_t)b*400 + 2*s + 1] = st;
  }
}

// ==================================================================================
extern "C" void kernel_launch(void* const* d_in, const int* in_sizes, int n_in,
                              void* d_out, int out_size, void* d_ws, size_t ws_size,
                              hipStream_t stream)
{
  const float* enc   = (const float*)d_in[0];
  const float* inp   = (const float*)d_in[1];
  const float* Wpre1 = (const float*)d_in[2];
  const float* bpre1 = (const float*)d_in[3];
  const float* Wpre2 = (const float*)d_in[4];
  const float* bpre2 = (const float*)d_in[5];
  const float* Wmem  = (const float*)d_in[6];
  const float* Wiha  = (const float*)d_in[7];
  const float* Whha  = (const float*)d_in[8];
  const float* biha  = (const float*)d_in[9];
  const float* bhha  = (const float*)d_in[10];
  const float* Wq    = (const float*)d_in[11];
  const float* Wconv = (const float*)d_in[12];
  const float* Wloc  = (const float*)d_in[13];
  const float* vv    = (const float*)d_in[14];
  const float* Wihd  = (const float*)d_in[15];
  const float* Whhd  = (const float*)d_in[16];
  const float* bihd  = (const float*)d_in[17];
  const float* bhhd  = (const float*)d_in[18];
  const float* Wmel  = (const float*)d_in[19];
  const float* bmel  = (const float*)d_in[20];
  const float* Wstop = (const float*)d_in[21];
  const float* bstop = (const float*)d_in[22];
  float* out = (float*)d_out;

  char* pp = (char*)d_ws;
  auto carve = [&](size_t bytes)->char*{
    char* r = (char*)(((uintptr_t)pp + 255) & ~(uintptr_t)255);
    pp = r + bytes;
    return r;
  };
  bf16*  enc_bf  = (bf16*) carve((size_t)64*200*512*2);
  float* pm      = (float*)carve((size_t)64*200*128*4);
  bf16*  decin   = (bf16*) carve((size_t)12800*96*2);
  bf16*  h1      = (bf16*) carve((size_t)12800*256*2);
  bf16*  pall    = (bf16*) carve((size_t)12800*256*2);
  bf16*  Wp1b    = (bf16*) carve((size_t)256*96*2);
  bf16*  Wp2b    = (bf16*) carve((size_t)256*256*2);
  bf16*  Wmemb   = (bf16*) carve((size_t)128*512*2);
  bf16*  Wqb     = (bf16*) carve((size_t)128*1024*2);
  bf16*  Wca     = (bf16*) carve((size_t)4096*KA*2);
  bf16*  Wcd     = (bf16*) carve((size_t)4096*KD*2);
  bf16*  Wmc     = (bf16*) carve((size_t)176*1536*2);
  float* biasa   = (float*)carve(4096*4);
  float* biasd   = (float*)carve(4096*4);
  float* bias176 = (float*)carve(176*4);
  bf16*  proj    = (bf16*) carve((size_t)12800*1536*2);
  float* meltmp  = (float*)carve((size_t)12800*176*4);
  float* ga      = (float*)carve((size_t)64*4096*4);
  float* gd      = (float*)carve((size_t)64*4096*4);
  // zeroed-every-launch state block (contiguous)
  bf16*  xa  = (bf16*) carve((size_t)64*1792*2);
  bf16*  xd  = (bf16*) carve((size_t)64*2560*2);
  float* ac  = (float*)carve((size_t)64*1024*4);
  float* dc  = (float*)carve((size_t)64*1024*4);
  unsigned* cnt = (unsigned*)carve(256);
  size_t zbytes = (size_t)((char*)cnt + 256 - (char*)xa);
  hipMemsetAsync(xa, 0, zbytes, stream);

  // ---- prologue: conversions / packing ----
  cvt_kernel<<<(6553600+255)/256,256,0,stream>>>(enc,   enc_bf, 6553600);
  cvt_kernel<<<(131072+255)/256, 256,0,stream>>>(Wq,    Wqb,    131072);
  cvt_kernel<<<(65536+255)/256,  256,0,stream>>>(Wmem,  Wmemb,  65536);
  cvt_kernel<<<(65536+255)/256,  256,0,stream>>>(Wpre2, Wp2b,   65536);
  cvt_pad_kernel<<<(256*96+255)/256,256,0,stream>>>(Wpre1, Wp1b, 256, 80, 96);
  cat_cvt_kernel<<<(4096*KA+255)/256,256,0,stream>>>(Wiha, 768,  Whha, 1024, Wca, 4096);
  cat_cvt_kernel<<<(4096*KD+255)/256,256,0,stream>>>(Wihd, 1536, Whhd, 1024, Wcd, 4096);
  build_wmelcat<<<(176*1536+255)/256,256,0,stream>>>(Wmel, Wstop, Wmc);
  build_misc<<<(8368+255)/256,256,0,stream>>>(biha,bhha,biasa, bihd,bhhd,biasd, bmel,bstop,bias176);
  build_decin<<<(12800*96+255)/256,256,0,stream>>>(inp, decin);

  // ---- prologue: batched GEMMs ----
  gemm_k<1,1><<<800,256,0,stream>>>(decin, Wp1b, bpre1, nullptr, h1, 12800,256,96, 200);
  gemm_k<1,1><<<800,256,0,stream>>>(h1, Wp2b, bpre2, nullptr, pall, 12800,256,256, 200);
  gemm_k<0,0><<<400,256,0,stream>>>(enc_bf, Wmemb, nullptr, pm, nullptr, 12800,128,512, 200);

  // ---- the whole 200-step scan as ONE persistent kernel (weights in LDS) ----
  static int attr_done = 0;
  hipFuncSetAttribute((const void*)decoder_scan,
                      hipFuncAttributeMaxDynamicSharedMemorySize, DSMEM);
  (void)attr_done;
  float* out_attn = out + 2073600;
  decoder_scan<<<NBLK,256,DSMEM,stream>>>(pall, Wca, Wcd, biasa, biasd,
                                          Wqb, Wconv, Wloc, vv, pm, enc_bf,
                                          xa, xd, ga, gd, ac, dc,
                                          proj, out_attn, cnt);

  // ---- epilogue: mel/stop projection + scatter ----
  gemm_k<0,0><<<550,256,0,stream>>>(proj, Wmc, bias176, meltmp, nullptr, 12800,176,1536, 200);
  scatter_out<<<(12800*160+12800+255)/256,256,0,stream>>>(meltmp, out);
}

// Round 6
// 27480.124 us; speedup vs baseline: 1.1493x; 1.1493x over previous
//
#include <hip/hip_runtime.h>
#include <hip/hip_bf16.h>
#include <stdint.h>

// Dims
#define STEPS  200
#define KA     1792   // p(256) + ctx(512) + ah(1024)
#define KD     2560   // ctx(512) + ah(1024) + dh(1024)  (ring order!)
#define NBLK   256
#define JLA    56     // KA/32 frag-iters (all LDS)
#define JLD    80     // KD/32 frag-iters (all LDS, 160 KiB)
#define WLDS_A (JLA*2*64*16)   // 114688 B
#define DSMEM  163840          // 160 KiB
#define SLOT   (64*2560)       // ring slot elements (bf16)

using bf16 = __bf16;
typedef __bf16 bf16x8 __attribute__((ext_vector_type(8)));
typedef float  f32x4  __attribute__((ext_vector_type(4)));
typedef unsigned int       u32;
typedef unsigned long long u64;

union U2f { u64 q; float f[2]; };
union U2h { u32 u; bf16 h[2]; };
union U4h { u32 u[2]; bf16 h[4]; };

#define MFMA16(a,b,c) __builtin_amdgcn_mfma_f32_16x16x32_bf16((a),(b),(c),0,0,0)

__device__ __forceinline__ float sigf(float x){ return 1.f/(1.f+__expf(-x)); }
__device__ __forceinline__ float tanhf_(float x){
  float ax = fabsf(x);
  float e  = __expf(-2.f*ax);
  float t  = (1.f-e)/(1.f+e);
  return x < 0.f ? -t : t;
}

// coherent (agent-scope, LLC) accessors — used ONLY for gates + ring writes
__device__ __forceinline__ u64 ldq(const u64* p){
  return __hip_atomic_load((u64*)p, __ATOMIC_RELAXED, __HIP_MEMORY_SCOPE_AGENT);
}
__device__ __forceinline__ void stf(float* p, float v){
  __hip_atomic_store(p, v, __ATOMIC_RELAXED, __HIP_MEMORY_SCOPE_AGENT);
}
__device__ __forceinline__ void stu(u32* p, u32 v){
  __hip_atomic_store(p, v, __ATOMIC_RELAXED, __HIP_MEMORY_SCOPE_AGENT);
}

// ---------------- prologue conversion kernels ----------------
__global__ void cvt_kernel(const float* __restrict__ s, bf16* __restrict__ d, int n){
  int i = blockIdx.x*256 + threadIdx.x;
  if (i < n) d[i] = (bf16)s[i];
}
__global__ void cvt_pad_kernel(const float* __restrict__ s, bf16* __restrict__ d,
                               int rows, int cin, int cout){
  int i = blockIdx.x*256 + threadIdx.x;
  if (i >= rows*cout) return;
  int r = i / cout, c = i % cout;
  d[i] = (bf16)(c < cin ? s[(size_t)r*cin + c] : 0.f);
}
__global__ void cat_cvt_kernel(const float* __restrict__ s1, int c1,
                               const float* __restrict__ s2, int c2,
                               bf16* __restrict__ d, int rows){
  int C = c1 + c2;
  int i = blockIdx.x*256 + threadIdx.x;
  if (i >= rows*C) return;
  int r = i / C, c = i % C;
  float v = (c < c1) ? s1[(size_t)r*c1 + c] : s2[(size_t)r*c2 + (c - c1)];
  d[i] = (bf16)v;
}
// Wd repacked to ring k-order [ctx(512) | ah(1024) | dh(1024)]
__global__ void build_wcd2(const float* __restrict__ Wihd, const float* __restrict__ Whhd,
                           bf16* __restrict__ d){
  int i = blockIdx.x*256 + threadIdx.x;
  if (i >= 4096*2560) return;
  int r = i / 2560, c = i % 2560;
  float v;
  if (c < 512)        v = Wihd[(size_t)r*1536 + 1024 + c];
  else if (c < 1536)  v = Wihd[(size_t)r*1536 + (c - 512)];
  else                v = Whhd[(size_t)r*1024 + (c - 1536)];
  d[i] = (bf16)v;
}
__global__ void build_wmelcat(const float* __restrict__ Wmel, const float* __restrict__ Wstop,
                              bf16* __restrict__ d){
  int i = blockIdx.x*256 + threadIdx.x;
  if (i >= 176*1536) return;
  int r = i / 1536, c = i % 1536;
  float v = (r < 160) ? Wmel[(size_t)r*1536 + c] : (r == 160 ? Wstop[c] : 0.f);
  d[i] = (bf16)v;
}
__global__ void build_misc(const float* biha, const float* bhha, float* biasa,
                           const float* bihd, const float* bhhd, float* biasd,
                           const float* bmel, const float* bstop, float* bias176){
  int i = blockIdx.x*256 + threadIdx.x;
  if (i < 4096) biasa[i] = biha[i] + bhha[i];
  else if (i < 8192) { int j = i-4096; biasd[j] = bihd[j] + bhhd[j]; }
  else if (i < 8192+176) {
    int j = i - 8192;
    bias176[j] = (j < 160) ? bmel[j] : (j == 160 ? bstop[0] : 0.f);
  }
}
__global__ void build_decin(const float* __restrict__ inp, bf16* __restrict__ d){
  int i = blockIdx.x*256 + threadIdx.x;
  if (i >= 12800*96) return;
  int row = i / 96, c = i % 96;
  int s = row >> 6, b = row & 63;
  float v = 0.f;
  if (c < 80 && s > 0) v = inp[((size_t)b*400 + (2*s - 1))*80 + c];
  d[i] = (bf16)v;
}

// ---------------- generic MFMA GEMM (prologue/epilogue batched use) ----------------
template<int ACT, int OBF>
__global__ __launch_bounds__(256)
void gemm_k(const bf16* __restrict__ A, const bf16* __restrict__ Bm,
            const float* __restrict__ bias, float* __restrict__ Cf,
            bf16* __restrict__ Cb, int M, int N, int K, int MT)
{
  int wid = blockIdx.x*4 + (threadIdx.x >> 6);
  if (wid >= MT*(N >> 4)) return;
  int wm = wid % MT, wn = wid / MT;
  int l = threadIdx.x & 63, lo = l & 15, hi = l >> 4;
  const bf16* Bp = Bm + (size_t)(wn*16 + lo)*K + hi*8;
  const bf16* Ap = A  + (size_t)(wm*64 + lo)*K + hi*8;
  f32x4 acc0 = {0,0,0,0}, acc1 = {0,0,0,0}, acc2 = {0,0,0,0}, acc3 = {0,0,0,0};
  for (int k = 0; k < K; k += 32){
    bf16x8 bb = *(const bf16x8*)(Bp + k);
    bf16x8 a0 = *(const bf16x8*)(Ap + k);
    bf16x8 a1 = *(const bf16x8*)(Ap + (size_t)16*K + k);
    bf16x8 a2 = *(const bf16x8*)(Ap + (size_t)32*K + k);
    bf16x8 a3 = *(const bf16x8*)(Ap + (size_t)48*K + k);
    acc0 = MFMA16(a0, bb, acc0);
    acc1 = MFMA16(a1, bb, acc1);
    acc2 = MFMA16(a2, bb, acc2);
    acc3 = MFMA16(a3, bb, acc3);
  }
  int n = wn*16 + lo;
  float bv = bias ? bias[n] : 0.f;
  int m0 = wm*64 + hi*4;
  #pragma unroll
  for (int mt = 0; mt < 4; ++mt){
    f32x4 av = (mt==0)?acc0:(mt==1)?acc1:(mt==2)?acc2:acc3;
    #pragma unroll
    for (int r = 0; r < 4; ++r){
      float v = av[r] + bv;
      if (ACT) v = fmaxf(v, 0.f);
      size_t idx = (size_t)(m0 + mt*16 + r)*N + n;
      if (OBF) Cb[idx] = (bf16)v; else Cf[idx] = v;
    }
  }
}

// ---------------- grid barrier (R4-proven: single counter, no cache nukes) --------
__device__ __forceinline__ void gridbar(unsigned* cnt, unsigned target){
  __syncthreads();
  if (threadIdx.x == 0){
    asm volatile("s_waitcnt vmcnt(0)" ::: "memory");
    __hip_atomic_fetch_add(cnt, 1u, __ATOMIC_RELAXED, __HIP_MEMORY_SCOPE_AGENT);
    while (__hip_atomic_load(cnt, __ATOMIC_RELAXED, __HIP_MEMORY_SCOPE_AGENT) < target)
      __builtin_amdgcn_s_sleep(2);
    asm volatile("" ::: "memory");
  }
  __syncthreads();
}

// ---------------- THE persistent scan kernel ---------------------------------------
// 256 blocks x 256 thr, 1/CU. Weights fully LDS-resident.
// Activation transport: write-once ring (slot s = ring + (s+1)*SLOT holds
// [ctx_s | ah_s | dh_{s-1}] per batch row, 2560 bf16 cols). Producers write sc1
// (LLC); consumers use PLAIN loads — safe because each slot's lines are
// first-touched only after the barrier that follows their write (no stale L1/L2
// copies can exist), and plain loads let the compiler pipeline deeply + share
// L2 fills across the 32 blocks of an XCD.
__global__ __launch_bounds__(256, 1)
void decoder_scan(const bf16* __restrict__ pall,
                  const bf16* __restrict__ Wa, const bf16* __restrict__ Wd2,
                  const float* __restrict__ biasa, const float* __restrict__ biasd,
                  const bf16* __restrict__ Wqb, const float* __restrict__ Wconv,
                  const float* __restrict__ Wloc, const float* __restrict__ vvp,
                  const float* __restrict__ pm, const bf16* __restrict__ enc_bf,
                  bf16* __restrict__ ring,
                  float* __restrict__ ga, float* __restrict__ gd,
                  float* __restrict__ ac, float* __restrict__ dc,
                  bf16* __restrict__ proj, float* __restrict__ out_attn,
                  unsigned* __restrict__ cnt)
{
  extern __shared__ char smem[];
  const int tid = threadIdx.x;
  const int l = tid & 63, lo = l & 15, hi = l >> 4;
  const int wv = tid >> 6;

  const bool isA  = blockIdx.x < 128;
  const int  bq   = isA ? blockIdx.x : blockIdx.x - 128;
  const int  n0   = bq * 32;
  const int  K    = isA ? KA : KD;
  const int  JL   = isA ? JLA : JLD;
  const bf16* Wg  = isA ? Wa : Wd2;
  float*      G   = isA ? ga : gd;
  bf16* wlds = (bf16*)smem;

  // phase-B LDS overlay (blocks 0-63; above A-weights 112 KiB)
  char* pb = smem + WLDS_A;
  bf16*  ahs  = (bf16*)pb;              // 2048 B
  float* locb = (float*)(pb + 2048);    // 25600
  float* awl  = (float*)(pb + 27648);   // 1024
  float* qp   = (float*)(pb + 28672);   // 1024
  float* qv   = (float*)(pb + 29696);   // 512
  float* es   = (float*)(pb + 30208);   // 1024
  float* sred = (float*)(pb + 31232);   // 64

  // ---- preload weights into LDS (fragment-major: frag (j,t) at (j*2+t)*64+lane) ----
  for (int j = wv; j < JL; j += 4){
    #pragma unroll
    for (int t = 0; t < 2; ++t){
      bf16x8 v = *(const bf16x8*)(Wg + (size_t)(n0 + t*16 + lo)*K + j*32 + hi*8);
      *(bf16x8*)(wlds + ((size_t)(j*2 + t)*64 + l)*8) = v;
    }
  }

  unsigned nb = 0;

  if (blockIdx.x < 64){
    if (tid < 256) awl[tid] = 0.f;
  }
  __syncthreads();
  gridbar(cnt, ++nb * NBLK);

  for (int i = 0; i <= STEPS; ++i){
    const bf16* slotPrev = ring + (size_t)i*SLOT;        // state of step i-1
    bf16*       slotCur  = ring + (size_t)(i+1)*SLOT;    // state of step i

    // =========================== phase A: gate GEMM ===========================
    const bool work = isA ? (i < STEPS) : (i > 0);
    if (work){
      const int m0 = wv*16;
      const bf16* wl = wlds + (size_t)l*8;
      f32x4 acc0 = {0,0,0,0}, acc1 = {0,0,0,0};
      const bf16* Xp = slotPrev + (size_t)(m0 + lo)*2560 + hi*8;
      if (isA){
        // region 1: prenet p_i straight from pall (plain, read-only)
        const bf16* Pp = pall + ((size_t)i*64 + m0 + lo)*256 + hi*8;
        #pragma unroll
        for (int j = 0; j < 8; ++j){
          bf16x8 a  = *(const bf16x8*)(Pp + j*32);
          bf16x8 b0 = *(const bf16x8*)(wl + (size_t)(2*j    )*512);
          bf16x8 b1 = *(const bf16x8*)(wl + (size_t)(2*j + 1)*512);
          acc0 = MFMA16(a, b0, acc0);
          acc1 = MFMA16(a, b1, acc1);
        }
        // region 2: [ctx | ah] from ring slot (plain, write-once slot)
        #pragma unroll 8
        for (int j = 8; j < JLA; ++j){
          bf16x8 a  = *(const bf16x8*)(Xp + (j - 8)*32);
          bf16x8 b0 = *(const bf16x8*)(wl + (size_t)(2*j    )*512);
          bf16x8 b1 = *(const bf16x8*)(wl + (size_t)(2*j + 1)*512);
          acc0 = MFMA16(a, b0, acc0);
          acc1 = MFMA16(a, b1, acc1);
        }
      } else {
        // D: full [ctx | ah | dh] row (weights pre-permuted to match)
        #pragma unroll 8
        for (int j = 0; j < JLD; ++j){
          bf16x8 a  = *(const bf16x8*)(Xp + j*32);
          bf16x8 b0 = *(const bf16x8*)(wl + (size_t)(2*j    )*512);
          bf16x8 b1 = *(const bf16x8*)(wl + (size_t)(2*j + 1)*512);
          acc0 = MFMA16(a, b0, acc0);
          acc1 = MFMA16(a, b1, acc1);
        }
      }
      #pragma unroll
      for (int r = 0; r < 4; ++r){
        stf(&G[(size_t)(m0 + hi*4 + r)*4096 + n0 +      lo], acc0[r]);
        stf(&G[(size_t)(m0 + hi*4 + r)*4096 + n0 + 16 + lo], acc1[r]);
      }
    }
    gridbar(cnt, ++nb * NBLK);

    // =========================== phase B: state + attention ====================
    if (blockIdx.x < 64){
      const int b = blockIdx.x;
      const int u0 = tid*4;
      if (i > 0){
        // dec LSTM cell (step i-1): coherent gate reads (R4-proven pattern)
        const u64* gp = (const u64*)(gd + (size_t)b*4096);
        float gg[16];
        #pragma unroll
        for (int g = 0; g < 4; ++g){
          U2f x0, x1;
          x0.q = ldq(gp + ((g*1024 + u0) >> 1));
          x1.q = ldq(gp + ((g*1024 + u0) >> 1) + 1);
          gg[g*4+0]=x0.f[0]; gg[g*4+1]=x0.f[1]; gg[g*4+2]=x1.f[0]; gg[g*4+3]=x1.f[1];
        }
        U4h hp;
        #pragma unroll
        for (int j = 0; j < 4; ++j){
          int u = u0 + j;
          float iv=gg[j]+biasd[u], fv=gg[4+j]+biasd[1024+u];
          float gv=gg[8+j]+biasd[2048+u], ov=gg[12+j]+biasd[3072+u];
          float c = sigf(fv)*dc[b*1024+u] + sigf(iv)*tanhf_(gv);
          float h = sigf(ov)*tanhf_(c);
          dc[b*1024+u] = c;
          bf16 hb = (bf16)h;
          hp.h[j] = hb;
          proj[((size_t)(i-1)*64 + b)*1536 + u] = hb;
        }
        // dh_{i-1} -> slot i cols [1536,2560)
        u32* xp = (u32*)(slotCur + (size_t)b*2560 + 1536 + u0);
        stu(xp, hp.u[0]); stu(xp+1, hp.u[1]);
      }
      if (i < STEPS){
        // attn LSTM cell (step i)
        {
          const u64* gp = (const u64*)(ga + (size_t)b*4096);
          float gg[16];
          #pragma unroll
          for (int g = 0; g < 4; ++g){
            U2f x0, x1;
            x0.q = ldq(gp + ((g*1024 + u0) >> 1));
            x1.q = ldq(gp + ((g*1024 + u0) >> 1) + 1);
            gg[g*4+0]=x0.f[0]; gg[g*4+1]=x0.f[1]; gg[g*4+2]=x1.f[0]; gg[g*4+3]=x1.f[1];
          }
          U4h hp;
          #pragma unroll
          for (int j = 0; j < 4; ++j){
            int u = u0 + j;
            float iv=gg[j]+biasa[u], fv=gg[4+j]+biasa[1024+u];
            float gv=gg[8+j]+biasa[2048+u], ov=gg[12+j]+biasa[3072+u];
            float c = sigf(fv)*ac[b*1024+u] + sigf(iv)*tanhf_(gv);
            float h = sigf(ov)*tanhf_(c);
            ac[b*1024+u] = c;
            bf16 hb = (bf16)h;
            hp.h[j] = hb;
            ahs[u] = hb;
          }
          // ah_i -> slot i cols [512,1536)
          u32* xpa = (u32*)(slotCur + (size_t)b*2560 + 512 + u0);
          stu(xpa, hp.u[0]); stu(xpa+1, hp.u[1]);
        }
        __syncthreads();  // ahs ready
        // conv1d(31) of previous alignment
        for (int it = tid; it < 6400; it += 256){
          int f = it & 31, tl = it >> 5;
          float s = 0.f;
          #pragma unroll
          for (int j = 0; j < 31; ++j){
            int tt = tl + j - 15;
            if ((unsigned)tt < 200u) s += awl[tt]*Wconv[f*31+j];
          }
          locb[tl*32 + f] = s;
        }
        // q = ah @ Wq^T
        {
          int a = tid & 127, hf = tid >> 7;
          const bf16* wr = Wqb + (size_t)a*1024 + hf*512;
          float s = 0.f;
          for (int k2 = 0; k2 < 512; k2 += 8){
            bf16x8 x = *(const bf16x8*)(&ahs[hf*512 + k2]);
            bf16x8 y = *(const bf16x8*)(wr + k2);
            #pragma unroll
            for (int e = 0; e < 8; ++e) s += (float)x[e]*(float)y[e];
          }
          qp[tid] = s;
        }
        __syncthreads();
        if (tid < 128) qv[tid] = qp[tid] + qp[tid+128];
        __syncthreads();
        // energies
        for (int tl = wv; tl < 200; tl += 4){
          const float* pmrow = pm + ((size_t)b*200 + tl)*128;
          float s = 0.f;
          #pragma unroll
          for (int half = 0; half < 2; ++half){
            int a = l + half*64;
            float x = qv[a] + pmrow[a];
            const float* wl2 = Wloc + a*32;
            #pragma unroll
            for (int f = 0; f < 32; ++f) x += locb[tl*32 + f]*wl2[f];
            s += vvp[a]*tanhf_(x);
          }
          #pragma unroll
          for (int o = 32; o; o >>= 1) s += __shfl_xor(s, o);
          if (l == 0) es[tl] = s;
        }
        __syncthreads();
        // softmax over 200
        {
          float e0 = (tid < 200) ? es[tid] : -3.0e38f;
          float m = e0;
          #pragma unroll
          for (int o = 32; o; o >>= 1) m = fmaxf(m, __shfl_xor(m, o));
          if (l == 0) sred[wv] = m;
          __syncthreads();
          m = fmaxf(fmaxf(sred[0],sred[1]), fmaxf(sred[2],sred[3]));
          float p = (tid < 200) ? __expf(e0 - m) : 0.f;
          float ss = p;
          #pragma unroll
          for (int o = 32; o; o >>= 1) ss += __shfl_xor(ss, o);
          __syncthreads();
          if (l == 0) sred[wv] = ss;
          __syncthreads();
          ss = sred[0]+sred[1]+sred[2]+sred[3];
          float aval = p / ss;
          if (tid < 200){
            awl[tid] = aval;
            out_attn[((size_t)b*200 + i)*200 + tid] = aval;
          }
        }
        __syncthreads();
        // context = align @ enc  -> slot i cols [0,512)
        {
          const u32* ep = (const u32*)(enc_bf + (size_t)b*102400) + tid;
          float s0 = 0.f, s1 = 0.f;
          #pragma unroll 4
          for (int t = 0; t < 200; ++t){
            U2h w; w.u = ep[(size_t)t*256];
            float a = awl[t];
            s0 += a*(float)w.h[0];
            s1 += a*(float)w.h[1];
          }
          U2h cb; cb.h[0] = (bf16)s0; cb.h[1] = (bf16)s1;
          stu((u32*)(slotCur + (size_t)b*2560) + tid, cb.u);
          *((u32*)(proj + ((size_t)i*64 + b)*1536 + 1024) + tid) = cb.u;
        }
      }
    }
    gridbar(cnt, ++nb * NBLK);
  }
}

// ---------------- epilogue scatter -------------------------------------------------
__global__ void scatter_out(const float* __restrict__ mt_, float* __restrict__ out){
  int i = blockIdx.x*256 + threadIdx.x;
  const int NMEL = 12800*160;
  if (i < NMEL){
    int sb = i / 160, j = i % 160;
    int s = sb >> 6, b = sb & 63;
    int r = j / 80, mm = j % 80;
    out[((size_t)b*400 + 2*s + r)*80 + mm] = mt_[(size_t)sb*176 + j];
  } else if (i < NMEL + 12800){
    int sb = i - NMEL;
    int s = sb >> 6, b = sb & 63;
    float st = sigf(mt_[(size_t)sb*176 + 160]);
    float* so = out + 2048000;
    so[(size_t)b*400 + 2*s]     = st;
    so[(size_t)b*400 + 2*s + 1] = st;
  }
}

// ==================================================================================
extern "C" void kernel_launch(void* const* d_in, const int* in_sizes, int n_in,
                              void* d_out, int out_size, void* d_ws, size_t ws_size,
                              hipStream_t stream)
{
  const float* enc   = (const float*)d_in[0];
  const float* inp   = (const float*)d_in[1];
  const float* Wpre1 = (const float*)d_in[2];
  const float* bpre1 = (const float*)d_in[3];
  const float* Wpre2 = (const float*)d_in[4];
  const float* bpre2 = (const float*)d_in[5];
  const float* Wmem  = (const float*)d_in[6];
  const float* Wiha  = (const float*)d_in[7];
  const float* Whha  = (const float*)d_in[8];
  const float* biha  = (const float*)d_in[9];
  const float* bhha  = (const float*)d_in[10];
  const float* Wq    = (const float*)d_in[11];
  const float* Wconv = (const float*)d_in[12];
  const float* Wloc  = (const float*)d_in[13];
  const float* vv    = (const float*)d_in[14];
  const float* Wihd  = (const float*)d_in[15];
  const float* Whhd  = (const float*)d_in[16];
  const float* bihd  = (const float*)d_in[17];
  const float* bhhd  = (const float*)d_in[18];
  const float* Wmel  = (const float*)d_in[19];
  const float* bmel  = (const float*)d_in[20];
  const float* Wstop = (const float*)d_in[21];
  const float* bstop = (const float*)d_in[22];
  float* out = (float*)d_out;

  char* pp = (char*)d_ws;
  auto carve = [&](size_t bytes)->char*{
    char* r = (char*)(((uintptr_t)pp + 255) & ~(uintptr_t)255);
    pp = r + bytes;
    return r;
  };
  bf16*  enc_bf  = (bf16*) carve((size_t)64*200*512*2);
  float* pm      = (float*)carve((size_t)64*200*128*4);
  bf16*  decin   = (bf16*) carve((size_t)12800*96*2);
  bf16*  h1      = (bf16*) carve((size_t)12800*256*2);
  bf16*  pall    = (bf16*) carve((size_t)12800*256*2);
  bf16*  Wp1b    = (bf16*) carve((size_t)256*96*2);
  bf16*  Wp2b    = (bf16*) carve((size_t)256*256*2);
  bf16*  Wmemb   = (bf16*) carve((size_t)128*512*2);
  bf16*  Wqb     = (bf16*) carve((size_t)128*1024*2);
  bf16*  Wca     = (bf16*) carve((size_t)4096*KA*2);
  bf16*  Wcd2    = (bf16*) carve((size_t)4096*KD*2);
  bf16*  Wmc     = (bf16*) carve((size_t)176*1536*2);
  float* biasa   = (float*)carve(4096*4);
  float* biasd   = (float*)carve(4096*4);
  float* bias176 = (float*)carve(176*4);
  bf16*  proj    = (bf16*) carve((size_t)12800*1536*2);
  float* meltmp  = (float*)carve((size_t)12800*176*4);
  float* ga      = (float*)carve((size_t)64*4096*4);
  float* gd      = (float*)carve((size_t)64*4096*4);
  // zeroed-every-launch block
  float* ac  = (float*)carve((size_t)64*1024*4);
  float* dc  = (float*)carve((size_t)64*1024*4);
  unsigned* cnt = (unsigned*)carve(4096);
  size_t zbytes = (size_t)((char*)cnt + 4096 - (char*)ac);
  // write-once activation ring: 202 slots of [64][2560] bf16
  bf16*  ring = (bf16*)carve((size_t)202*SLOT*2);
  hipMemsetAsync(ac, 0, zbytes, stream);
  hipMemsetAsync(ring, 0, (size_t)SLOT*2, stream);   // zero slot -1 only

  // ---- prologue: conversions / packing ----
  cvt_kernel<<<(6553600+255)/256,256,0,stream>>>(enc,   enc_bf, 6553600);
  cvt_kernel<<<(131072+255)/256, 256,0,stream>>>(Wq,    Wqb,    131072);
  cvt_kernel<<<(65536+255)/256,  256,0,stream>>>(Wmem,  Wmemb,  65536);
  cvt_kernel<<<(65536+255)/256,  256,0,stream>>>(Wpre2, Wp2b,   65536);
  cvt_pad_kernel<<<(256*96+255)/256,256,0,stream>>>(Wpre1, Wp1b, 256, 80, 96);
  cat_cvt_kernel<<<(4096*KA+255)/256,256,0,stream>>>(Wiha, 768,  Whha, 1024, Wca, 4096);
  build_wcd2<<<(4096*2560+255)/256,256,0,stream>>>(Wihd, Whhd, Wcd2);
  build_wmelcat<<<(176*1536+255)/256,256,0,stream>>>(Wmel, Wstop, Wmc);
  build_misc<<<(8368+255)/256,256,0,stream>>>(biha,bhha,biasa, bihd,bhhd,biasd, bmel,bstop,bias176);
  build_decin<<<(12800*96+255)/256,256,0,stream>>>(inp, decin);

  // ---- prologue: batched GEMMs ----
  gemm_k<1,1><<<800,256,0,stream>>>(decin, Wp1b, bpre1, nullptr, h1, 12800,256,96, 200);
  gemm_k<1,1><<<800,256,0,stream>>>(h1, Wp2b, bpre2, nullptr, pall, 12800,256,256, 200);
  gemm_k<0,0><<<400,256,0,stream>>>(enc_bf, Wmemb, nullptr, pm, nullptr, 12800,128,512, 200);

  // ---- the whole 200-step scan as ONE persistent kernel ----
  hipFuncSetAttribute((const void*)decoder_scan,
                      hipFuncAttributeMaxDynamicSharedMemorySize, DSMEM);
  float* out_attn = out + 2073600;
  decoder_scan<<<NBLK,256,DSMEM,stream>>>(pall, Wca, Wcd2, biasa, biasd,
                                          Wqb, Wconv, Wloc, vv, pm, enc_bf,
                                          ring, ga, gd, ac, dc,
                                          proj, out_attn, cnt);

  // ---- epilogue: mel/stop projection + scatter ----
  gemm_k<0,0><<<550,256,0,stream>>>(proj, Wmc, bias176, meltmp, nullptr, 12800,176,1536, 200);
  scatter_out<<<(12800*160+12800+255)/256,256,0,stream>>>(meltmp, out);
}

// Round 7
// 26694.266 us; speedup vs baseline: 1.1831x; 1.0294x over previous
//
#include <hip/hip_runtime.h>
#include <hip/hip_bf16.h>
#include <stdint.h>

// Dims
#define STEPS  200
#define KA     1792   // p(256) + ctx(512) + ah(1024)
#define KD     2560   // ctx(512) + ah(1024) + dh(1024)  (ring order!)
#define NBLK   256
#define JLA    56     // KA/32 frag-iters (all LDS)
#define JLD    80     // KD/32 frag-iters (all LDS, 160 KiB)
#define WLDS_A (JLA*2*64*16)   // 114688 B
#define DSMEM  163840          // 160 KiB
#define SLOT   (64*2560)       // ring slot elements (bf16)

using bf16 = __bf16;
typedef __bf16 bf16x8 __attribute__((ext_vector_type(8)));
typedef float  f32x4  __attribute__((ext_vector_type(4)));
typedef int    i32x4  __attribute__((ext_vector_type(4)));
typedef unsigned int       u32;
typedef unsigned long long u64;

union U16 { i32x4 i; bf16x8 v; float f[4]; u32 u[4]; };
union U2h { u32 u; bf16 h[2]; };
union U4h { u32 u[2]; bf16 h[4]; };

#define MFMA16(a,b,c) __builtin_amdgcn_mfma_f32_16x16x32_bf16((a),(b),(c),0,0,0)

// coherent (LLC, sc1) 16B load under manual scheduling; pair with WAITV0 (full drain)
#define GLD16(dst, addr) \
  asm volatile("global_load_dwordx4 %0, %1, off sc1" : "=&v"(dst) : "v"(addr))
#define WAITV0 \
  { asm volatile("s_waitcnt vmcnt(0)" ::: "memory"); __builtin_amdgcn_sched_barrier(0); }

__device__ __forceinline__ float sigf(float x){ return 1.f/(1.f+__expf(-x)); }
__device__ __forceinline__ float tanhf_(float x){
  float ax = fabsf(x);
  float e  = __expf(-2.f*ax);
  float t  = (1.f-e)/(1.f+e);
  return x < 0.f ? -t : t;
}

__device__ __forceinline__ void stf(float* p, float v){
  __hip_atomic_store(p, v, __ATOMIC_RELAXED, __HIP_MEMORY_SCOPE_AGENT);
}
__device__ __forceinline__ void stu(u32* p, u32 v){
  __hip_atomic_store(p, v, __ATOMIC_RELAXED, __HIP_MEMORY_SCOPE_AGENT);
}

// ---------------- prologue conversion kernels ----------------
__global__ void cvt_kernel(const float* __restrict__ s, bf16* __restrict__ d, int n){
  int i = blockIdx.x*256 + threadIdx.x;
  if (i < n) d[i] = (bf16)s[i];
}
__global__ void cvt_pad_kernel(const float* __restrict__ s, bf16* __restrict__ d,
                               int rows, int cin, int cout){
  int i = blockIdx.x*256 + threadIdx.x;
  if (i >= rows*cout) return;
  int r = i / cout, c = i % cout;
  d[i] = (bf16)(c < cin ? s[(size_t)r*cin + c] : 0.f);
}
__global__ void cat_cvt_kernel(const float* __restrict__ s1, int c1,
                               const float* __restrict__ s2, int c2,
                               bf16* __restrict__ d, int rows){
  int C = c1 + c2;
  int i = blockIdx.x*256 + threadIdx.x;
  if (i >= rows*C) return;
  int r = i / C, c = i % C;
  float v = (c < c1) ? s1[(size_t)r*c1 + c] : s2[(size_t)r*c2 + (c - c1)];
  d[i] = (bf16)v;
}
// Wd repacked to ring k-order [ctx(512) | ah(1024) | dh(1024)]
__global__ void build_wcd2(const float* __restrict__ Wihd, const float* __restrict__ Whhd,
                           bf16* __restrict__ d){
  int i = blockIdx.x*256 + threadIdx.x;
  if (i >= 4096*2560) return;
  int r = i / 2560, c = i % 2560;
  float v;
  if (c < 512)        v = Wihd[(size_t)r*1536 + 1024 + c];
  else if (c < 1536)  v = Wihd[(size_t)r*1536 + (c - 512)];
  else                v = Whhd[(size_t)r*1024 + (c - 1536)];
  d[i] = (bf16)v;
}
__global__ void build_wmelcat(const float* __restrict__ Wmel, const float* __restrict__ Wstop,
                              bf16* __restrict__ d){
  int i = blockIdx.x*256 + threadIdx.x;
  if (i >= 176*1536) return;
  int r = i / 1536, c = i % 1536;
  float v = (r < 160) ? Wmel[(size_t)r*1536 + c] : (r == 160 ? Wstop[c] : 0.f);
  d[i] = (bf16)v;
}
__global__ void build_misc(const float* biha, const float* bhha, float* biasa,
                           const float* bihd, const float* bhhd, float* biasd,
                           const float* bmel, const float* bstop, float* bias176){
  int i = blockIdx.x*256 + threadIdx.x;
  if (i < 4096) biasa[i] = biha[i] + bhha[i];
  else if (i < 8192) { int j = i-4096; biasd[j] = bihd[j] + bhhd[j]; }
  else if (i < 8192+176) {
    int j = i - 8192;
    bias176[j] = (j < 160) ? bmel[j] : (j == 160 ? bstop[0] : 0.f);
  }
}
__global__ void build_decin(const float* __restrict__ inp, bf16* __restrict__ d){
  int i = blockIdx.x*256 + threadIdx.x;
  if (i >= 12800*96) return;
  int row = i / 96, c = i % 96;
  int s = row >> 6, b = row & 63;
  float v = 0.f;
  if (c < 80 && s > 0) v = inp[((size_t)b*400 + (2*s - 1))*80 + c];
  d[i] = (bf16)v;
}

// ---------------- generic MFMA GEMM (prologue/epilogue batched use) ----------------
template<int ACT, int OBF>
__global__ __launch_bounds__(256)
void gemm_k(const bf16* __restrict__ A, const bf16* __restrict__ Bm,
            const float* __restrict__ bias, float* __restrict__ Cf,
            bf16* __restrict__ Cb, int M, int N, int K, int MT)
{
  int wid = blockIdx.x*4 + (threadIdx.x >> 6);
  if (wid >= MT*(N >> 4)) return;
  int wm = wid % MT, wn = wid / MT;
  int l = threadIdx.x & 63, lo = l & 15, hi = l >> 4;
  const bf16* Bp = Bm + (size_t)(wn*16 + lo)*K + hi*8;
  const bf16* Ap = A  + (size_t)(wm*64 + lo)*K + hi*8;
  f32x4 acc0 = {0,0,0,0}, acc1 = {0,0,0,0}, acc2 = {0,0,0,0}, acc3 = {0,0,0,0};
  for (int k = 0; k < K; k += 32){
    bf16x8 bb = *(const bf16x8*)(Bp + k);
    bf16x8 a0 = *(const bf16x8*)(Ap + k);
    bf16x8 a1 = *(const bf16x8*)(Ap + (size_t)16*K + k);
    bf16x8 a2 = *(const bf16x8*)(Ap + (size_t)32*K + k);
    bf16x8 a3 = *(const bf16x8*)(Ap + (size_t)48*K + k);
    acc0 = MFMA16(a0, bb, acc0);
    acc1 = MFMA16(a1, bb, acc1);
    acc2 = MFMA16(a2, bb, acc2);
    acc3 = MFMA16(a3, bb, acc3);
  }
  int n = wn*16 + lo;
  float bv = bias ? bias[n] : 0.f;
  int m0 = wm*64 + hi*4;
  #pragma unroll
  for (int mt = 0; mt < 4; ++mt){
    f32x4 av = (mt==0)?acc0:(mt==1)?acc1:(mt==2)?acc2:acc3;
    #pragma unroll
    for (int r = 0; r < 4; ++r){
      float v = av[r] + bv;
      if (ACT) v = fmaxf(v, 0.f);
      size_t idx = (size_t)(m0 + mt*16 + r)*N + n;
      if (OBF) Cb[idx] = (bf16)v; else Cf[idx] = v;
    }
  }
}

// ---------------- grid barrier: flag-broadcast, NO RMW contention ------------------
// cnt[0..255]  : per-block arrival epochs (sc1 stores)
// cnt[320]     : release epoch (written by block 0, lane 0)
// Block 0 wave 0 aggregates flags via dwordx4 sc1 loads; everyone polls release.
__device__ __forceinline__ void gridbar(unsigned* cnt, unsigned nb){
  __syncthreads();
  const int tid = threadIdx.x;
  if (blockIdx.x == 0){
    if (tid < 64){
      if (tid == 0)
        __hip_atomic_store(&cnt[0], nb, __ATOMIC_RELAXED, __HIP_MEMORY_SCOPE_AGENT);
      const unsigned* fp = cnt + tid*4;
      for (;;){
        U16 f;
        GLD16(f.i, (const void*)fp);
        WAITV0;
        bool ok = (f.u[0] >= nb) & (f.u[1] >= nb) & (f.u[2] >= nb) & (f.u[3] >= nb);
        if (__all(ok)) break;
        __builtin_amdgcn_s_sleep(1);
      }
      if (tid == 0)
        __hip_atomic_store(&cnt[320], nb, __ATOMIC_RELAXED, __HIP_MEMORY_SCOPE_AGENT);
    }
  } else if (tid == 0){
    __hip_atomic_store(&cnt[blockIdx.x], nb, __ATOMIC_RELAXED, __HIP_MEMORY_SCOPE_AGENT);
    while (__hip_atomic_load(&cnt[320], __ATOMIC_RELAXED, __HIP_MEMORY_SCOPE_AGENT) < nb)
      __builtin_amdgcn_s_sleep(1);
    asm volatile("" ::: "memory");
  }
  __syncthreads();
}

// ---------------- THE persistent scan kernel ---------------------------------------
// 256 blocks x 256 thr, 1/CU. Weights fully LDS-resident.
// Ring transport (R6-proven): write-once slots, sc1 producers, plain consumers.
// Gate reads: batched GLD16 + vmcnt(0) (one LLC round trip per phase-B cell pair).
__global__ __launch_bounds__(256, 1)
void decoder_scan(const bf16* __restrict__ pall,
                  const bf16* __restrict__ Wa, const bf16* __restrict__ Wd2,
                  const float* __restrict__ biasa, const float* __restrict__ biasd,
                  const bf16* __restrict__ Wqb, const float* __restrict__ Wconv,
                  const float* __restrict__ Wloc, const float* __restrict__ vvp,
                  const float* __restrict__ pm, const bf16* __restrict__ enc_bf,
                  bf16* __restrict__ ring,
                  float* __restrict__ ga, float* __restrict__ gd,
                  float* __restrict__ ac, float* __restrict__ dc,
                  bf16* __restrict__ proj, float* __restrict__ out_attn,
                  unsigned* __restrict__ cnt)
{
  extern __shared__ char smem[];
  const int tid = threadIdx.x;
  const int l = tid & 63, lo = l & 15, hi = l >> 4;
  const int wv = tid >> 6;

  const bool isA  = blockIdx.x < 128;
  const int  bq   = isA ? blockIdx.x : blockIdx.x - 128;
  const int  n0   = bq * 32;
  const int  K    = isA ? KA : KD;
  const int  JL   = isA ? JLA : JLD;
  const bf16* Wg  = isA ? Wa : Wd2;
  float*      G   = isA ? ga : gd;
  bf16* wlds = (bf16*)smem;

  // phase-B LDS overlay (blocks 0-63; above A-weights 112 KiB)
  char* pb = smem + WLDS_A;
  bf16*  ahs  = (bf16*)pb;              // 2048 B
  float* locb = (float*)(pb + 2048);    // 25600
  float* awl  = (float*)(pb + 27648);   // 1024
  float* qp   = (float*)(pb + 28672);   // 1024
  float* qv   = (float*)(pb + 29696);   // 512
  float* es   = (float*)(pb + 30208);   // 1024
  float* sred = (float*)(pb + 31232);   // 64

  // ---- preload weights into LDS (fragment-major) ----
  for (int j = wv; j < JL; j += 4){
    #pragma unroll
    for (int t = 0; t < 2; ++t){
      bf16x8 v = *(const bf16x8*)(Wg + (size_t)(n0 + t*16 + lo)*K + j*32 + hi*8);
      *(bf16x8*)(wlds + ((size_t)(j*2 + t)*64 + l)*8) = v;
    }
  }

  unsigned nb = 0;

  if (blockIdx.x < 64){
    if (tid < 256) awl[tid] = 0.f;
  }
  __syncthreads();
  gridbar(cnt, ++nb);

  for (int i = 0; i <= STEPS; ++i){
    const bf16* slotPrev = ring + (size_t)i*SLOT;        // [ctx|ah|dh] of step i-1
    bf16*       slotCur  = ring + (size_t)(i+1)*SLOT;

    // =========================== phase A: gate GEMM ===========================
    const bool work = isA ? (i < STEPS) : (i > 0);
    if (work){
      const int m0 = wv*16;
      const bf16* wl = wlds + (size_t)l*8;
      f32x4 acc0 = {0,0,0,0}, acc1 = {0,0,0,0};
      const bf16* Xp = slotPrev + (size_t)(m0 + lo)*2560 + hi*8;
      if (isA){
        const bf16* Pp = pall + ((size_t)i*64 + m0 + lo)*256 + hi*8;
        #pragma unroll
        for (int j = 0; j < 8; ++j){
          bf16x8 a  = *(const bf16x8*)(Pp + j*32);
          bf16x8 b0 = *(const bf16x8*)(wl + (size_t)(2*j    )*512);
          bf16x8 b1 = *(const bf16x8*)(wl + (size_t)(2*j + 1)*512);
          acc0 = MFMA16(a, b0, acc0);
          acc1 = MFMA16(a, b1, acc1);
        }
        #pragma unroll 8
        for (int j = 8; j < JLA; ++j){
          bf16x8 a  = *(const bf16x8*)(Xp + (j - 8)*32);
          bf16x8 b0 = *(const bf16x8*)(wl + (size_t)(2*j    )*512);
          bf16x8 b1 = *(const bf16x8*)(wl + (size_t)(2*j + 1)*512);
          acc0 = MFMA16(a, b0, acc0);
          acc1 = MFMA16(a, b1, acc1);
        }
      } else {
        #pragma unroll 8
        for (int j = 0; j < JLD; ++j){
          bf16x8 a  = *(const bf16x8*)(Xp + j*32);
          bf16x8 b0 = *(const bf16x8*)(wl + (size_t)(2*j    )*512);
          bf16x8 b1 = *(const bf16x8*)(wl + (size_t)(2*j + 1)*512);
          acc0 = MFMA16(a, b0, acc0);
          acc1 = MFMA16(a, b1, acc1);
        }
      }
      #pragma unroll
      for (int r = 0; r < 4; ++r){
        stf(&G[(size_t)(m0 + hi*4 + r)*4096 + n0 +      lo], acc0[r]);
        stf(&G[(size_t)(m0 + hi*4 + r)*4096 + n0 + 16 + lo], acc1[r]);
      }
    }
    // conv1d(31) of previous alignment — off the B critical path (uses awl of step i-1)
    if (blockIdx.x < 64 && i < STEPS){
      for (int it = tid; it < 6400; it += 256){
        int f = it & 31, tl = it >> 5;
        float s = 0.f;
        #pragma unroll
        for (int j = 0; j < 31; ++j){
          int tt = tl + j - 15;
          if ((unsigned)tt < 200u) s += awl[tt]*Wconv[f*31+j];
        }
        locb[tl*32 + f] = s;
      }
    }
    gridbar(cnt, ++nb);

    // =========================== phase B: state + attention ====================
    if (blockIdx.x < 64){
      const int b = blockIdx.x;
      const int u0 = tid*4;
      const bool doD = (i > 0), doA = (i < STEPS);
      U16 d0,d1,d2,d3, a0,a1,a2,a3;
      if (doD){
        const float* gp = gd + (size_t)b*4096 + u0;
        GLD16(d0.i, (const void*)(gp));
        GLD16(d1.i, (const void*)(gp + 1024));
        GLD16(d2.i, (const void*)(gp + 2048));
        GLD16(d3.i, (const void*)(gp + 3072));
      }
      if (doA){
        const float* gp = ga + (size_t)b*4096 + u0;
        GLD16(a0.i, (const void*)(gp));
        GLD16(a1.i, (const void*)(gp + 1024));
        GLD16(a2.i, (const void*)(gp + 2048));
        GLD16(a3.i, (const void*)(gp + 3072));
      }
      WAITV0;
      if (doD){
        U4h hp;
        #pragma unroll
        for (int j = 0; j < 4; ++j){
          int u = u0 + j;
          float iv=d0.f[j]+biasd[u], fv=d1.f[j]+biasd[1024+u];
          float gv=d2.f[j]+biasd[2048+u], ov=d3.f[j]+biasd[3072+u];
          float c = sigf(fv)*dc[b*1024+u] + sigf(iv)*tanhf_(gv);
          float h = sigf(ov)*tanhf_(c);
          dc[b*1024+u] = c;
          bf16 hb = (bf16)h;
          hp.h[j] = hb;
          proj[((size_t)(i-1)*64 + b)*1536 + u] = hb;
        }
        u32* xp = (u32*)(slotCur + (size_t)b*2560 + 1536 + u0);
        stu(xp, hp.u[0]); stu(xp+1, hp.u[1]);
      }
      if (doA){
        {
          U4h hp;
          #pragma unroll
          for (int j = 0; j < 4; ++j){
            int u = u0 + j;
            float iv=a0.f[j]+biasa[u], fv=a1.f[j]+biasa[1024+u];
            float gv=a2.f[j]+biasa[2048+u], ov=a3.f[j]+biasa[3072+u];
            float c = sigf(fv)*ac[b*1024+u] + sigf(iv)*tanhf_(gv);
            float h = sigf(ov)*tanhf_(c);
            ac[b*1024+u] = c;
            bf16 hb = (bf16)h;
            hp.h[j] = hb;
            ahs[u] = hb;
          }
          u32* xpa = (u32*)(slotCur + (size_t)b*2560 + 512 + u0);
          stu(xpa, hp.u[0]); stu(xpa+1, hp.u[1]);
        }
        __syncthreads();  // ahs ready
        // q = ah @ Wq^T
        {
          int a = tid & 127, hf = tid >> 7;
          const bf16* wr = Wqb + (size_t)a*1024 + hf*512;
          float s = 0.f;
          for (int k2 = 0; k2 < 512; k2 += 8){
            bf16x8 x = *(const bf16x8*)(&ahs[hf*512 + k2]);
            bf16x8 y = *(const bf16x8*)(wr + k2);
            #pragma unroll
            for (int e = 0; e < 8; ++e) s += (float)x[e]*(float)y[e];
          }
          qp[tid] = s;
        }
        __syncthreads();
        if (tid < 128) qv[tid] = qp[tid] + qp[tid+128];
        __syncthreads();
        // energies (locb precomputed in phase-A window)
        for (int tl = wv; tl < 200; tl += 4){
          const float* pmrow = pm + ((size_t)b*200 + tl)*128;
          float s = 0.f;
          #pragma unroll
          for (int half = 0; half < 2; ++half){
            int a = l + half*64;
            float x = qv[a] + pmrow[a];
            const float* wl2 = Wloc + a*32;
            #pragma unroll
            for (int f = 0; f < 32; ++f) x += locb[tl*32 + f]*wl2[f];
            s += vvp[a]*tanhf_(x);
          }
          #pragma unroll
          for (int o = 32; o; o >>= 1) s += __shfl_xor(s, o);
          if (l == 0) es[tl] = s;
        }
        __syncthreads();
        // softmax over 200
        {
          float e0 = (tid < 200) ? es[tid] : -3.0e38f;
          float m = e0;
          #pragma unroll
          for (int o = 32; o; o >>= 1) m = fmaxf(m, __shfl_xor(m, o));
          if (l == 0) sred[wv] = m;
          __syncthreads();
          m = fmaxf(fmaxf(sred[0],sred[1]), fmaxf(sred[2],sred[3]));
          float p = (tid < 200) ? __expf(e0 - m) : 0.f;
          float ss = p;
          #pragma unroll
          for (int o = 32; o; o >>= 1) ss += __shfl_xor(ss, o);
          __syncthreads();
          if (l == 0) sred[wv] = ss;
          __syncthreads();
          ss = sred[0]+sred[1]+sred[2]+sred[3];
          float aval = p / ss;
          if (tid < 200){
            awl[tid] = aval;
            out_attn[((size_t)b*200 + i)*200 + tid] = aval;
          }
        }
        __syncthreads();
        // context = align @ enc  -> slot i cols [0,512)
        {
          const u32* ep = (const u32*)(enc_bf + (size_t)b*102400) + tid;
          float s0 = 0.f, s1 = 0.f;
          #pragma unroll 4
          for (int t = 0; t < 200; ++t){
            U2h w; w.u = ep[(size_t)t*256];
            float a = awl[t];
            s0 += a*(float)w.h[0];
            s1 += a*(float)w.h[1];
          }
          U2h cb; cb.h[0] = (bf16)s0; cb.h[1] = (bf16)s1;
          stu((u32*)(slotCur + (size_t)b*2560) + tid, cb.u);
          *((u32*)(proj + ((size_t)i*64 + b)*1536 + 1024) + tid) = cb.u;
        }
      }
    }
    gridbar(cnt, ++nb);
  }
}

// ---------------- epilogue scatter -------------------------------------------------
__global__ void scatter_out(const float* __restrict__ mt_, float* __restrict__ out){
  int i = blockIdx.x*256 + threadIdx.x;
  const int NMEL = 12800*160;
  if (i < NMEL){
    int sb = i / 160, j = i % 160;
    int s = sb >> 6, b = sb & 63;
    int r = j / 80, mm = j % 80;
    out[((size_t)b*400 + 2*s + r)*80 + mm] = mt_[(size_t)sb*176 + j];
  } else if (i < NMEL + 12800){
    int sb = i - NMEL;
    int s = sb >> 6, b = sb & 63;
    float st = sigf(mt_[(size_t)sb*176 + 160]);
    float* so = out + 2048000;
    so[(size_t)b*400 + 2*s]     = st;
    so[(size_t)b*400 + 2*s + 1] = st;
  }
}

// ==================================================================================
extern "C" void kernel_launch(void* const* d_in, const int* in_sizes, int n_in,
                              void* d_out, int out_size, void* d_ws, size_t ws_size,
                              hipStream_t stream)
{
  const float* enc   = (const float*)d_in[0];
  const float* inp   = (const float*)d_in[1];
  const float* Wpre1 = (const float*)d_in[2];
  const float* bpre1 = (const float*)d_in[3];
  const float* Wpre2 = (const float*)d_in[4];
  const float* bpre2 = (const float*)d_in[5];
  const float* Wmem  = (const float*)d_in[6];
  const float* Wiha  = (const float*)d_in[7];
  const float* Whha  = (const float*)d_in[8];
  const float* biha  = (const float*)d_in[9];
  const float* bhha  = (const float*)d_in[10];
  const float* Wq    = (const float*)d_in[11];
  const float* Wconv = (const float*)d_in[12];
  const float* Wloc  = (const float*)d_in[13];
  const float* vv    = (const float*)d_in[14];
  const float* Wihd  = (const float*)d_in[15];
  const float* Whhd  = (const float*)d_in[16];
  const float* bihd  = (const float*)d_in[17];
  const float* bhhd  = (const float*)d_in[18];
  const float* Wmel  = (const float*)d_in[19];
  const float* bmel  = (const float*)d_in[20];
  const float* Wstop = (const float*)d_in[21];
  const float* bstop = (const float*)d_in[22];
  float* out = (float*)d_out;

  char* pp = (char*)d_ws;
  auto carve = [&](size_t bytes)->char*{
    char* r = (char*)(((uintptr_t)pp + 255) & ~(uintptr_t)255);
    pp = r + bytes;
    return r;
  };
  bf16*  enc_bf  = (bf16*) carve((size_t)64*200*512*2);
  float* pm      = (float*)carve((size_t)64*200*128*4);
  bf16*  decin   = (bf16*) carve((size_t)12800*96*2);
  bf16*  h1      = (bf16*) carve((size_t)12800*256*2);
  bf16*  pall    = (bf16*) carve((size_t)12800*256*2);
  bf16*  Wp1b    = (bf16*) carve((size_t)256*96*2);
  bf16*  Wp2b    = (bf16*) carve((size_t)256*256*2);
  bf16*  Wmemb   = (bf16*) carve((size_t)128*512*2);
  bf16*  Wqb     = (bf16*) carve((size_t)128*1024*2);
  bf16*  Wca     = (bf16*) carve((size_t)4096*KA*2);
  bf16*  Wcd2    = (bf16*) carve((size_t)4096*KD*2);
  bf16*  Wmc     = (bf16*) carve((size_t)176*1536*2);
  float* biasa   = (float*)carve(4096*4);
  float* biasd   = (float*)carve(4096*4);
  float* bias176 = (float*)carve(176*4);
  bf16*  proj    = (bf16*) carve((size_t)12800*1536*2);
  float* meltmp  = (float*)carve((size_t)12800*176*4);
  float* ga      = (float*)carve((size_t)64*4096*4);
  float* gd      = (float*)carve((size_t)64*4096*4);
  // zeroed-every-launch block
  float* ac  = (float*)carve((size_t)64*1024*4);
  float* dc  = (float*)carve((size_t)64*1024*4);
  unsigned* cnt = (unsigned*)carve(4096);
  size_t zbytes = (size_t)((char*)cnt + 4096 - (char*)ac);
  // write-once activation ring: 202 slots of [64][2560] bf16
  bf16*  ring = (bf16*)carve((size_t)202*SLOT*2);
  hipMemsetAsync(ac, 0, zbytes, stream);
  hipMemsetAsync(ring, 0, (size_t)SLOT*2, stream);   // zero slot -1 only

  // ---- prologue: conversions / packing ----
  cvt_kernel<<<(6553600+255)/256,256,0,stream>>>(enc,   enc_bf, 6553600);
  cvt_kernel<<<(131072+255)/256, 256,0,stream>>>(Wq,    Wqb,    131072);
  cvt_kernel<<<(65536+255)/256,  256,0,stream>>>(Wmem,  Wmemb,  65536);
  cvt_kernel<<<(65536+255)/256,  256,0,stream>>>(Wpre2, Wp2b,   65536);
  cvt_pad_kernel<<<(256*96+255)/256,256,0,stream>>>(Wpre1, Wp1b, 256, 80, 96);
  cat_cvt_kernel<<<(4096*KA+255)/256,256,0,stream>>>(Wiha, 768,  Whha, 1024, Wca, 4096);
  build_wcd2<<<(4096*2560+255)/256,256,0,stream>>>(Wihd, Whhd, Wcd2);
  build_wmelcat<<<(176*1536+255)/256,256,0,stream>>>(Wmel, Wstop, Wmc);
  build_misc<<<(8368+255)/256,256,0,stream>>>(biha,bhha,biasa, bihd,bhhd,biasd, bmel,bstop,bias176);
  build_decin<<<(12800*96+255)/256,256,0,stream>>>(inp, decin);

  // ---- prologue: batched GEMMs ----
  gemm_k<1,1><<<800,256,0,stream>>>(decin, Wp1b, bpre1, nullptr, h1, 12800,256,96, 200);
  gemm_k<1,1><<<800,256,0,stream>>>(h1, Wp2b, bpre2, nullptr, pall, 12800,256,256, 200);
  gemm_k<0,0><<<400,256,0,stream>>>(enc_bf, Wmemb, nullptr, pm, nullptr, 12800,128,512, 200);

  // ---- the whole 200-step scan as ONE persistent kernel ----
  hipFuncSetAttribute((const void*)decoder_scan,
                      hipFuncAttributeMaxDynamicSharedMemorySize, DSMEM);
  float* out_attn = out + 2073600;
  decoder_scan<<<NBLK,256,DSMEM,stream>>>(pall, Wca, Wcd2, biasa, biasd,
                                          Wqb, Wconv, Wloc, vv, pm, enc_bf,
                                          ring, ga, gd, ac, dc,
                                          proj, out_attn, cnt);

  // ---- epilogue: mel/stop projection + scatter ----
  gemm_k<0,0><<<550,256,0,stream>>>(proj, Wmc, bias176, meltmp, nullptr, 12800,176,1536, 200);
  scatter_out<<<(12800*160+12800+255)/256,256,0,stream>>>(meltmp, out);
}

// Round 8
// 26690.503 us; speedup vs baseline: 1.1833x; 1.0001x over previous
//
#include <hip/hip_runtime.h>
#include <hip/hip_bf16.h>
#include <stdint.h>

// Dims
#define STEPS  200
#define KA     1792   // p(256) + ctx(512) + ah(1024)
#define KD     2560   // ctx(512) + ah(1024) + dh(1024)  (ring order!)
#define NBLK   256
#define JLA    56     // KA/32 frag-iters (all LDS)
#define JLD    80     // KD/32 frag-iters (all LDS, 160 KiB)
#define WLDS_A (JLA*2*64*16)   // 114688 B
#define DSMEM  163840          // 160 KiB
#define SLOT   (64*2560)       // ring slot elements (bf16)
#define RELBASE 1024           // u32 index of release lines (64 lines, 64B apart)

using bf16 = __bf16;
typedef __bf16 bf16x8 __attribute__((ext_vector_type(8)));
typedef float  f32x4  __attribute__((ext_vector_type(4)));
typedef int    i32x4  __attribute__((ext_vector_type(4)));
typedef unsigned int       u32;
typedef unsigned long long u64;

union U16 { i32x4 i; bf16x8 v; float f[4]; u32 u[4]; };
union U2h { u32 u; bf16 h[2]; };
union U4h { u32 u[2]; bf16 h[4]; };

#define MFMA16(a,b,c) __builtin_amdgcn_mfma_f32_16x16x32_bf16((a),(b),(c),0,0,0)

// coherent (LLC, sc1) 16B load under manual scheduling; pair with WAITV0 (full drain)
#define GLD16(dst, addr) \
  asm volatile("global_load_dwordx4 %0, %1, off sc1" : "=&v"(dst) : "v"(addr))
#define WAITV0 \
  { asm volatile("s_waitcnt vmcnt(0)" ::: "memory"); __builtin_amdgcn_sched_barrier(0); }

__device__ __forceinline__ float sigf(float x){ return 1.f/(1.f+__expf(-x)); }
__device__ __forceinline__ float tanhf_(float x){
  float ax = fabsf(x);
  float e  = __expf(-2.f*ax);
  float t  = (1.f-e)/(1.f+e);
  return x < 0.f ? -t : t;
}

__device__ __forceinline__ void stf(float* p, float v){
  __hip_atomic_store(p, v, __ATOMIC_RELAXED, __HIP_MEMORY_SCOPE_AGENT);
}
__device__ __forceinline__ void stu(u32* p, u32 v){
  __hip_atomic_store(p, v, __ATOMIC_RELAXED, __HIP_MEMORY_SCOPE_AGENT);
}

// ---------------- prologue conversion kernels ----------------
__global__ void cvt_kernel(const float* __restrict__ s, bf16* __restrict__ d, int n){
  int i = blockIdx.x*256 + threadIdx.x;
  if (i < n) d[i] = (bf16)s[i];
}
__global__ void cvt_pad_kernel(const float* __restrict__ s, bf16* __restrict__ d,
                               int rows, int cin, int cout){
  int i = blockIdx.x*256 + threadIdx.x;
  if (i >= rows*cout) return;
  int r = i / cout, c = i % cout;
  d[i] = (bf16)(c < cin ? s[(size_t)r*cin + c] : 0.f);
}
__global__ void cat_cvt_kernel(const float* __restrict__ s1, int c1,
                               const float* __restrict__ s2, int c2,
                               bf16* __restrict__ d, int rows){
  int C = c1 + c2;
  int i = blockIdx.x*256 + threadIdx.x;
  if (i >= rows*C) return;
  int r = i / C, c = i % C;
  float v = (c < c1) ? s1[(size_t)r*c1 + c] : s2[(size_t)r*c2 + (c - c1)];
  d[i] = (bf16)v;
}
// Wd repacked to ring k-order [ctx(512) | ah(1024) | dh(1024)]
__global__ void build_wcd2(const float* __restrict__ Wihd, const float* __restrict__ Whhd,
                           bf16* __restrict__ d){
  int i = blockIdx.x*256 + threadIdx.x;
  if (i >= 4096*2560) return;
  int r = i / 2560, c = i % 2560;
  float v;
  if (c < 512)        v = Wihd[(size_t)r*1536 + 1024 + c];
  else if (c < 1536)  v = Wihd[(size_t)r*1536 + (c - 512)];
  else                v = Whhd[(size_t)r*1024 + (c - 1536)];
  d[i] = (bf16)v;
}
__global__ void build_wmelcat(const float* __restrict__ Wmel, const float* __restrict__ Wstop,
                              bf16* __restrict__ d){
  int i = blockIdx.x*256 + threadIdx.x;
  if (i >= 176*1536) return;
  int r = i / 1536, c = i % 1536;
  float v = (r < 160) ? Wmel[(size_t)r*1536 + c] : (r == 160 ? Wstop[c] : 0.f);
  d[i] = (bf16)v;
}
__global__ void build_misc(const float* biha, const float* bhha, float* biasa,
                           const float* bihd, const float* bhhd, float* biasd,
                           const float* bmel, const float* bstop, float* bias176){
  int i = blockIdx.x*256 + threadIdx.x;
  if (i < 4096) biasa[i] = biha[i] + bhha[i];
  else if (i < 8192) { int j = i-4096; biasd[j] = bihd[j] + bhhd[j]; }
  else if (i < 8192+176) {
    int j = i - 8192;
    bias176[j] = (j < 160) ? bmel[j] : (j == 160 ? bstop[0] : 0.f);
  }
}
__global__ void build_decin(const float* __restrict__ inp, bf16* __restrict__ d){
  int i = blockIdx.x*256 + threadIdx.x;
  if (i >= 12800*96) return;
  int row = i / 96, c = i % 96;
  int s = row >> 6, b = row & 63;
  float v = 0.f;
  if (c < 80 && s > 0) v = inp[((size_t)b*400 + (2*s - 1))*80 + c];
  d[i] = (bf16)v;
}

// ---------------- generic MFMA GEMM (prologue/epilogue batched use) ----------------
template<int ACT, int OBF>
__global__ __launch_bounds__(256)
void gemm_k(const bf16* __restrict__ A, const bf16* __restrict__ Bm,
            const float* __restrict__ bias, float* __restrict__ Cf,
            bf16* __restrict__ Cb, int M, int N, int K, int MT)
{
  int wid = blockIdx.x*4 + (threadIdx.x >> 6);
  if (wid >= MT*(N >> 4)) return;
  int wm = wid % MT, wn = wid / MT;
  int l = threadIdx.x & 63, lo = l & 15, hi = l >> 4;
  const bf16* Bp = Bm + (size_t)(wn*16 + lo)*K + hi*8;
  const bf16* Ap = A  + (size_t)(wm*64 + lo)*K + hi*8;
  f32x4 acc0 = {0,0,0,0}, acc1 = {0,0,0,0}, acc2 = {0,0,0,0}, acc3 = {0,0,0,0};
  for (int k = 0; k < K; k += 32){
    bf16x8 bb = *(const bf16x8*)(Bp + k);
    bf16x8 a0 = *(const bf16x8*)(Ap + k);
    bf16x8 a1 = *(const bf16x8*)(Ap + (size_t)16*K + k);
    bf16x8 a2 = *(const bf16x8*)(Ap + (size_t)32*K + k);
    bf16x8 a3 = *(const bf16x8*)(Ap + (size_t)48*K + k);
    acc0 = MFMA16(a0, bb, acc0);
    acc1 = MFMA16(a1, bb, acc1);
    acc2 = MFMA16(a2, bb, acc2);
    acc3 = MFMA16(a3, bb, acc3);
  }
  int n = wn*16 + lo;
  float bv = bias ? bias[n] : 0.f;
  int m0 = wm*64 + hi*4;
  #pragma unroll
  for (int mt = 0; mt < 4; ++mt){
    f32x4 av = (mt==0)?acc0:(mt==1)?acc1:(mt==2)?acc2:acc3;
    #pragma unroll
    for (int r = 0; r < 4; ++r){
      float v = av[r] + bv;
      if (ACT) v = fmaxf(v, 0.f);
      size_t idx = (size_t)(m0 + mt*16 + r)*N + n;
      if (OBF) Cb[idx] = (bf16)v; else Cf[idx] = v;
    }
  }
}

// ---------------- grid barrier: flag-broadcast + 64 release lines ------------------
// cnt[0..255]        : per-block arrival epochs (packed; block0 reads in 1 wave-load)
// cnt[RELBASE+g*16]  : 64 release lines (64B apart); block g polls line g&63
__device__ __forceinline__ void gridbar(unsigned* cnt, unsigned nb){
  __syncthreads();
  const int tid = threadIdx.x;
  if (blockIdx.x == 0){
    if (tid < 64){
      if (tid == 0)
        __hip_atomic_store(&cnt[0], nb, __ATOMIC_RELAXED, __HIP_MEMORY_SCOPE_AGENT);
      const unsigned* fp = cnt + tid*4;
      for (;;){
        U16 f;
        GLD16(f.i, (const void*)fp);
        WAITV0;
        bool ok = (f.u[0] >= nb) & (f.u[1] >= nb) & (f.u[2] >= nb) & (f.u[3] >= nb);
        if (__all(ok)) break;
        __builtin_amdgcn_s_sleep(2);
      }
      __hip_atomic_store(&cnt[RELBASE + tid*16], nb, __ATOMIC_RELAXED,
                         __HIP_MEMORY_SCOPE_AGENT);
    }
  } else if (tid == 0){
    __hip_atomic_store(&cnt[blockIdx.x], nb, __ATOMIC_RELAXED, __HIP_MEMORY_SCOPE_AGENT);
    const unsigned g = blockIdx.x & 63u;
    while (__hip_atomic_load(&cnt[RELBASE + g*16], __ATOMIC_RELAXED,
                             __HIP_MEMORY_SCOPE_AGENT) < nb)
      __builtin_amdgcn_s_sleep(2);
    asm volatile("" ::: "memory");
  }
  __syncthreads();
}

// ---------------- THE persistent scan kernel ---------------------------------------
// 256 blocks x 256 thr, 1/CU. Weights fully LDS-resident.
// Ring transport (R6-proven): write-once slots, sc1 producers, plain consumers.
// Gate reads: batched GLD16 + vmcnt(0). Barrier: de-hotspotted release broadcast.
__global__ __launch_bounds__(256, 1)
void decoder_scan(const bf16* __restrict__ pall,
                  const bf16* __restrict__ Wa, const bf16* __restrict__ Wd2,
                  const float* __restrict__ biasa, const float* __restrict__ biasd,
                  const bf16* __restrict__ Wqb, const float* __restrict__ Wconv,
                  const float* __restrict__ Wloc, const float* __restrict__ vvp,
                  const float* __restrict__ pm, const bf16* __restrict__ enc_bf,
                  bf16* __restrict__ ring,
                  float* __restrict__ ga, float* __restrict__ gd,
                  float* __restrict__ ac, float* __restrict__ dc,
                  bf16* __restrict__ proj, float* __restrict__ out_attn,
                  unsigned* __restrict__ cnt)
{
  extern __shared__ char smem[];
  const int tid = threadIdx.x;
  const int l = tid & 63, lo = l & 15, hi = l >> 4;
  const int wv = tid >> 6;

  const bool isA  = blockIdx.x < 128;
  const int  bq   = isA ? blockIdx.x : blockIdx.x - 128;
  const int  n0   = bq * 32;
  const int  K    = isA ? KA : KD;
  const int  JL   = isA ? JLA : JLD;
  const bf16* Wg  = isA ? Wa : Wd2;
  float*      G   = isA ? ga : gd;
  bf16* wlds = (bf16*)smem;

  // phase-B LDS overlay (blocks 0-63; above A-weights 112 KiB)
  char* pb = smem + WLDS_A;
  bf16*  ahs   = (bf16*)pb;              // 2048 B
  float* locb  = (float*)(pb + 2048);    // 25600
  float* awl   = (float*)(pb + 27648);   // 1024
  float* qp    = (float*)(pb + 28672);   // 1024
  float* qv    = (float*)(pb + 29696);   // 512
  float* es    = (float*)(pb + 30208);   // 1024
  float* sred  = (float*)(pb + 31232);   // 64
  float* wlocT = (float*)(pb + 31296);   // 32x128 f32 = 16384 (ends at 162368)

  // ---- preload weights into LDS (fragment-major) ----
  for (int j = wv; j < JL; j += 4){
    #pragma unroll
    for (int t = 0; t < 2; ++t){
      bf16x8 v = *(const bf16x8*)(Wg + (size_t)(n0 + t*16 + lo)*K + j*32 + hi*8);
      *(bf16x8*)(wlds + ((size_t)(j*2 + t)*64 + l)*8) = v;
    }
  }

  unsigned nb = 0;

  if (blockIdx.x < 64){
    if (tid < 256) awl[tid] = 0.f;
    for (int it = tid; it < 4096; it += 256)
      wlocT[(it >> 7)*128 + (it & 127)] = Wloc[(it & 127)*32 + (it >> 7)];
  }
  __syncthreads();
  gridbar(cnt, ++nb);

  for (int i = 0; i <= STEPS; ++i){
    const bf16* slotPrev = ring + (size_t)i*SLOT;        // [ctx|ah|dh] of step i-1
    bf16*       slotCur  = ring + (size_t)(i+1)*SLOT;

    // =========================== phase A: gate GEMM ===========================
    const bool work = isA ? (i < STEPS) : (i > 0);
    if (work){
      const int m0 = wv*16;
      const bf16* wl = wlds + (size_t)l*8;
      f32x4 acc0 = {0,0,0,0}, acc1 = {0,0,0,0};
      const bf16* Xp = slotPrev + (size_t)(m0 + lo)*2560 + hi*8;
      if (isA){
        const bf16* Pp = pall + ((size_t)i*64 + m0 + lo)*256 + hi*8;
        #pragma unroll
        for (int j = 0; j < 8; ++j){
          bf16x8 a  = *(const bf16x8*)(Pp + j*32);
          bf16x8 b0 = *(const bf16x8*)(wl + (size_t)(2*j    )*512);
          bf16x8 b1 = *(const bf16x8*)(wl + (size_t)(2*j + 1)*512);
          acc0 = MFMA16(a, b0, acc0);
          acc1 = MFMA16(a, b1, acc1);
        }
        #pragma unroll 8
        for (int j = 8; j < JLA; ++j){
          bf16x8 a  = *(const bf16x8*)(Xp + (j - 8)*32);
          bf16x8 b0 = *(const bf16x8*)(wl + (size_t)(2*j    )*512);
          bf16x8 b1 = *(const bf16x8*)(wl + (size_t)(2*j + 1)*512);
          acc0 = MFMA16(a, b0, acc0);
          acc1 = MFMA16(a, b1, acc1);
        }
      } else {
        #pragma unroll 8
        for (int j = 0; j < JLD; ++j){
          bf16x8 a  = *(const bf16x8*)(Xp + j*32);
          bf16x8 b0 = *(const bf16x8*)(wl + (size_t)(2*j    )*512);
          bf16x8 b1 = *(const bf16x8*)(wl + (size_t)(2*j + 1)*512);
          acc0 = MFMA16(a, b0, acc0);
          acc1 = MFMA16(a, b1, acc1);
        }
      }
      #pragma unroll
      for (int r = 0; r < 4; ++r){
        stf(&G[(size_t)(m0 + hi*4 + r)*4096 + n0 +      lo], acc0[r]);
        stf(&G[(size_t)(m0 + hi*4 + r)*4096 + n0 + 16 + lo], acc1[r]);
      }
    }
    // conv1d(31) of previous alignment — in the A window (uses awl of step i-1)
    if (blockIdx.x < 64 && i < STEPS){
      for (int it = tid; it < 6400; it += 256){
        int f = it & 31, tl = it >> 5;
        float s = 0.f;
        #pragma unroll
        for (int j = 0; j < 31; ++j){
          int tt = tl + j - 15;
          if ((unsigned)tt < 200u) s += awl[tt]*Wconv[f*31+j];
        }
        locb[tl*32 + f] = s;
      }
    }
    gridbar(cnt, ++nb);

    // =========================== phase B: state + attention ====================
    if (blockIdx.x < 64){
      const int b = blockIdx.x;
      const int u0 = tid*4;
      const bool doD = (i > 0), doA = (i < STEPS);
      U16 d0,d1,d2,d3, a0,a1,a2,a3;
      if (doD){
        const float* gp = gd + (size_t)b*4096 + u0;
        GLD16(d0.i, (const void*)(gp));
        GLD16(d1.i, (const void*)(gp + 1024));
        GLD16(d2.i, (const void*)(gp + 2048));
        GLD16(d3.i, (const void*)(gp + 3072));
      }
      if (doA){
        const float* gp = ga + (size_t)b*4096 + u0;
        GLD16(a0.i, (const void*)(gp));
        GLD16(a1.i, (const void*)(gp + 1024));
        GLD16(a2.i, (const void*)(gp + 2048));
        GLD16(a3.i, (const void*)(gp + 3072));
      }
      WAITV0;
      if (doD){
        U4h hp;
        #pragma unroll
        for (int j = 0; j < 4; ++j){
          int u = u0 + j;
          float iv=d0.f[j]+biasd[u], fv=d1.f[j]+biasd[1024+u];
          float gv=d2.f[j]+biasd[2048+u], ov=d3.f[j]+biasd[3072+u];
          float c = sigf(fv)*dc[b*1024+u] + sigf(iv)*tanhf_(gv);
          float h = sigf(ov)*tanhf_(c);
          dc[b*1024+u] = c;
          bf16 hb = (bf16)h;
          hp.h[j] = hb;
          proj[((size_t)(i-1)*64 + b)*1536 + u] = hb;
        }
        u32* xp = (u32*)(slotCur + (size_t)b*2560 + 1536 + u0);
        stu(xp, hp.u[0]); stu(xp+1, hp.u[1]);
      }
      if (doA){
        {
          U4h hp;
          #pragma unroll
          for (int j = 0; j < 4; ++j){
            int u = u0 + j;
            float iv=a0.f[j]+biasa[u], fv=a1.f[j]+biasa[1024+u];
            float gv=a2.f[j]+biasa[2048+u], ov=a3.f[j]+biasa[3072+u];
            float c = sigf(fv)*ac[b*1024+u] + sigf(iv)*tanhf_(gv);
            float h = sigf(ov)*tanhf_(c);
            ac[b*1024+u] = c;
            bf16 hb = (bf16)h;
            hp.h[j] = hb;
            ahs[u] = hb;
          }
          u32* xpa = (u32*)(slotCur + (size_t)b*2560 + 512 + u0);
          stu(xpa, hp.u[0]); stu(xpa+1, hp.u[1]);
        }
        __syncthreads();  // ahs ready
        // q = ah @ Wq^T
        {
          int a = tid & 127, hf = tid >> 7;
          const bf16* wr = Wqb + (size_t)a*1024 + hf*512;
          float s = 0.f;
          for (int k2 = 0; k2 < 512; k2 += 8){
            bf16x8 x = *(const bf16x8*)(&ahs[hf*512 + k2]);
            bf16x8 y = *(const bf16x8*)(wr + k2);
            #pragma unroll
            for (int e = 0; e < 8; ++e) s += (float)x[e]*(float)y[e];
          }
          qp[tid] = s;
        }
        __syncthreads();
        if (tid < 128) qv[tid] = qp[tid] + qp[tid+128];
        __syncthreads();
        // energies (locb + wlocT both in LDS)
        for (int tl = wv; tl < 200; tl += 4){
          const float* pmrow = pm + ((size_t)b*200 + tl)*128;
          const float* lrow  = locb + tl*32;
          float s = 0.f;
          #pragma unroll
          for (int half = 0; half < 2; ++half){
            int a = l + half*64;
            float x = qv[a] + pmrow[a];
            const float* wc = wlocT + a;
            #pragma unroll
            for (int f = 0; f < 32; ++f) x += lrow[f]*wc[f*128];
            s += vvp[a]*tanhf_(x);
          }
          #pragma unroll
          for (int o = 32; o; o >>= 1) s += __shfl_xor(s, o);
          if (l == 0) es[tl] = s;
        }
        __syncthreads();
        // softmax over 200
        {
          float e0 = (tid < 200) ? es[tid] : -3.0e38f;
          float m = e0;
          #pragma unroll
          for (int o = 32; o; o >>= 1) m = fmaxf(m, __shfl_xor(m, o));
          if (l == 0) sred[wv] = m;
          __syncthreads();
          m = fmaxf(fmaxf(sred[0],sred[1]), fmaxf(sred[2],sred[3]));
          float p = (tid < 200) ? __expf(e0 - m) : 0.f;
          float ss = p;
          #pragma unroll
          for (int o = 32; o; o >>= 1) ss += __shfl_xor(ss, o);
          __syncthreads();
          if (l == 0) sred[wv] = ss;
          __syncthreads();
          ss = sred[0]+sred[1]+sred[2]+sred[3];
          float aval = p / ss;
          if (tid < 200){
            awl[tid] = aval;
            out_attn[((size_t)b*200 + i)*200 + tid] = aval;
          }
        }
        __syncthreads();
        // context = align @ enc  -> slot i cols [0,512)  (2 chains, unroll 8)
        {
          const u32* ep = (const u32*)(enc_bf + (size_t)b*102400) + tid;
          float x0=0.f, y0=0.f, x1=0.f, y1=0.f;
          #pragma unroll 8
          for (int t = 0; t < 200; t += 2){
            U2h w0; w0.u = ep[(size_t)t*256];
            U2h w1; w1.u = ep[(size_t)(t+1)*256];
            float al0 = awl[t], al1 = awl[t+1];
            x0 += al0*(float)w0.h[0]; y0 += al0*(float)w0.h[1];
            x1 += al1*(float)w1.h[0]; y1 += al1*(float)w1.h[1];
          }
          U2h cb; cb.h[0] = (bf16)(x0+x1); cb.h[1] = (bf16)(y0+y1);
          stu((u32*)(slotCur + (size_t)b*2560) + tid, cb.u);
          *((u32*)(proj + ((size_t)i*64 + b)*1536 + 1024) + tid) = cb.u;
        }
      }
    }
    gridbar(cnt, ++nb);
  }
}

// ---------------- epilogue scatter -------------------------------------------------
__global__ void scatter_out(const float* __restrict__ mt_, float* __restrict__ out){
  int i = blockIdx.x*256 + threadIdx.x;
  const int NMEL = 12800*160;
  if (i < NMEL){
    int sb = i / 160, j = i % 160;
    int s = sb >> 6, b = sb & 63;
    int r = j / 80, mm = j % 80;
    out[((size_t)b*400 + 2*s + r)*80 + mm] = mt_[(size_t)sb*176 + j];
  } else if (i < NMEL + 12800){
    int sb = i - NMEL;
    int s = sb >> 6, b = sb & 63;
    float st = sigf(mt_[(size_t)sb*176 + 160]);
    float* so = out + 2048000;
    so[(size_t)b*400 + 2*s]     = st;
    so[(size_t)b*400 + 2*s + 1] = st;
  }
}

// ==================================================================================
extern "C" void kernel_launch(void* const* d_in, const int* in_sizes, int n_in,
                              void* d_out, int out_size, void* d_ws, size_t ws_size,
                              hipStream_t stream)
{
  const float* enc   = (const float*)d_in[0];
  const float* inp   = (const float*)d_in[1];
  const float* Wpre1 = (const float*)d_in[2];
  const float* bpre1 = (const float*)d_in[3];
  const float* Wpre2 = (const float*)d_in[4];
  const float* bpre2 = (const float*)d_in[5];
  const float* Wmem  = (const float*)d_in[6];
  const float* Wiha  = (const float*)d_in[7];
  const float* Whha  = (const float*)d_in[8];
  const float* biha  = (const float*)d_in[9];
  const float* bhha  = (const float*)d_in[10];
  const float* Wq    = (const float*)d_in[11];
  const float* Wconv = (const float*)d_in[12];
  const float* Wloc  = (const float*)d_in[13];
  const float* vv    = (const float*)d_in[14];
  const float* Wihd  = (const float*)d_in[15];
  const float* Whhd  = (const float*)d_in[16];
  const float* bihd  = (const float*)d_in[17];
  const float* bhhd  = (const float*)d_in[18];
  const float* Wmel  = (const float*)d_in[19];
  const float* bmel  = (const float*)d_in[20];
  const float* Wstop = (const float*)d_in[21];
  const float* bstop = (const float*)d_in[22];
  float* out = (float*)d_out;

  char* pp = (char*)d_ws;
  auto carve = [&](size_t bytes)->char*{
    char* r = (char*)(((uintptr_t)pp + 255) & ~(uintptr_t)255);
    pp = r + bytes;
    return r;
  };
  bf16*  enc_bf  = (bf16*) carve((size_t)64*200*512*2);
  float* pm      = (float*)carve((size_t)64*200*128*4);
  bf16*  decin   = (bf16*) carve((size_t)12800*96*2);
  bf16*  h1      = (bf16*) carve((size_t)12800*256*2);
  bf16*  pall    = (bf16*) carve((size_t)12800*256*2);
  bf16*  Wp1b    = (bf16*) carve((size_t)256*96*2);
  bf16*  Wp2b    = (bf16*) carve((size_t)256*256*2);
  bf16*  Wmemb   = (bf16*) carve((size_t)128*512*2);
  bf16*  Wqb     = (bf16*) carve((size_t)128*1024*2);
  bf16*  Wca     = (bf16*) carve((size_t)4096*KA*2);
  bf16*  Wcd2    = (bf16*) carve((size_t)4096*KD*2);
  bf16*  Wmc     = (bf16*) carve((size_t)176*1536*2);
  float* biasa   = (float*)carve(4096*4);
  float* biasd   = (float*)carve(4096*4);
  float* bias176 = (float*)carve(176*4);
  bf16*  proj    = (bf16*) carve((size_t)12800*1536*2);
  float* meltmp  = (float*)carve((size_t)12800*176*4);
  float* ga      = (float*)carve((size_t)64*4096*4);
  float* gd      = (float*)carve((size_t)64*4096*4);
  // zeroed-every-launch block
  float* ac  = (float*)carve((size_t)64*1024*4);
  float* dc  = (float*)carve((size_t)64*1024*4);
  unsigned* cnt = (unsigned*)carve(16384);
  size_t zbytes = (size_t)((char*)cnt + 16384 - (char*)ac);
  // write-once activation ring: 202 slots of [64][2560] bf16
  bf16*  ring = (bf16*)carve((size_t)202*SLOT*2);
  hipMemsetAsync(ac, 0, zbytes, stream);
  hipMemsetAsync(ring, 0, (size_t)SLOT*2, stream);   // zero slot -1 only

  // ---- prologue: conversions / packing ----
  cvt_kernel<<<(6553600+255)/256,256,0,stream>>>(enc,   enc_bf, 6553600);
  cvt_kernel<<<(131072+255)/256, 256,0,stream>>>(Wq,    Wqb,    131072);
  cvt_kernel<<<(65536+255)/256,  256,0,stream>>>(Wmem,  Wmemb,  65536);
  cvt_kernel<<<(65536+255)/256,  256,0,stream>>>(Wpre2, Wp2b,   65536);
  cvt_pad_kernel<<<(256*96+255)/256,256,0,stream>>>(Wpre1, Wp1b, 256, 80, 96);
  cat_cvt_kernel<<<(4096*KA+255)/256,256,0,stream>>>(Wiha, 768,  Whha, 1024, Wca, 4096);
  build_wcd2<<<(4096*2560+255)/256,256,0,stream>>>(Wihd, Whhd, Wcd2);
  build_wmelcat<<<(176*1536+255)/256,256,0,stream>>>(Wmel, Wstop, Wmc);
  build_misc<<<(8368+255)/256,256,0,stream>>>(biha,bhha,biasa, bihd,bhhd,biasd, bmel,bstop,bias176);
  build_decin<<<(12800*96+255)/256,256,0,stream>>>(inp, decin);

  // ---- prologue: batched GEMMs ----
  gemm_k<1,1><<<800,256,0,stream>>>(decin, Wp1b, bpre1, nullptr, h1, 12800,256,96, 200);
  gemm_k<1,1><<<800,256,0,stream>>>(h1, Wp2b, bpre2, nullptr, pall, 12800,256,256, 200);
  gemm_k<0,0><<<400,256,0,stream>>>(enc_bf, Wmemb, nullptr, pm, nullptr, 12800,128,512, 200);

  // ---- the whole 200-step scan as ONE persistent kernel ----
  hipFuncSetAttribute((const void*)decoder_scan,
                      hipFuncAttributeMaxDynamicSharedMemorySize, DSMEM);
  float* out_attn = out + 2073600;
  decoder_scan<<<NBLK,256,DSMEM,stream>>>(pall, Wca, Wcd2, biasa, biasd,
                                          Wqb, Wconv, Wloc, vv, pm, enc_bf,
                                          ring, ga, gd, ac, dc,
                                          proj, out_attn, cnt);

  // ---- epilogue: mel/stop projection + scatter ----
  gemm_k<0,0><<<550,256,0,stream>>>(proj, Wmc, bias176, meltmp, nullptr, 12800,176,1536, 200);
  scatter_out<<<(12800*160+12800+255)/256,256,0,stream>>>(meltmp, out);
}